// Round 2
// 808.982 us; speedup vs baseline: 1.0169x; 1.0169x over previous
//
#include <hip/hip_runtime.h>

// Problem constants (from reference)
#define NN     50000
#define NFEAT  512
#define HIDD   128
#define NE     1600000
#define NB     ((NN + 255) / 256)   // 196 blocks for per-node arrays
#define NPART  8                    // row partitions ~ XCDs
#define RPP    (NN / NPART)         // 6250 rows per partition

typedef __attribute__((ext_vector_type(8))) short    bf16x8;
typedef __attribute__((ext_vector_type(4))) float    f32x4;
typedef __attribute__((ext_vector_type(4))) unsigned short us4;

__device__ inline unsigned short f2bf(float f) {   // fp32 -> bf16 RNE
  unsigned int u = __float_as_uint(f);
  u += 0x7FFFu + ((u >> 16) & 1u);
  return (unsigned short)(u >> 16);
}

__device__ inline void fma4(float4& a, float v, const float4& d) {
  a.x = fmaf(v, d.x, a.x);
  a.y = fmaf(v, d.y, a.y);
  a.z = fmaf(v, d.z, a.z);
  a.w = fmaf(v, d.w, a.w);
}

// ---------------------------------------------------------------------------
// Histogram: counts[row[i]]++  (int atomics)
// ---------------------------------------------------------------------------
__global__ __launch_bounds__(256) void hist_kernel(
    const int* __restrict__ row, int* __restrict__ counts, int e) {
  int i = blockIdx.x * blockDim.x + threadIdx.x;
  if (i < e) atomicAdd(&counts[row[i]], 1);
}

// ---------------------------------------------------------------------------
// Scan phase 1: per-block sums of counts -> bsum[block]
// ---------------------------------------------------------------------------
__global__ __launch_bounds__(256) void block_sum_kernel(
    const int* __restrict__ counts, int* __restrict__ bsum, int n) {
  __shared__ int ws[4];
  int i = blockIdx.x * 256 + threadIdx.x;
  int lane = threadIdx.x & 63, wid = threadIdx.x >> 6;
  int v = (i < n) ? counts[i] : 0;
#pragma unroll
  for (int off = 32; off > 0; off >>= 1) v += __shfl_down(v, off, 64);
  if (lane == 0) ws[wid] = v;
  __syncthreads();
  if (threadIdx.x == 0) bsum[blockIdx.x] = ws[0] + ws[1] + ws[2] + ws[3];
}

// ---------------------------------------------------------------------------
// Scan phase 2: single block, exclusive-scan nb partials in place;
// write grand total to rowptr[NN].
// ---------------------------------------------------------------------------
__global__ __launch_bounds__(256) void scan_partials_kernel(
    int* __restrict__ bsum, int* __restrict__ rowptr, int nb, int nfull) {
  __shared__ int ws[4];
  int t = threadIdx.x;
  int lane = t & 63, wid = t >> 6;
  int v = (t < nb) ? bsum[t] : 0;
  int incl = v;
#pragma unroll
  for (int off = 1; off < 64; off <<= 1) {
    int u = __shfl_up(incl, off, 64);
    if (lane >= off) incl += u;
  }
  if (lane == 63) ws[wid] = incl;
  __syncthreads();
  int wprefix = 0;
  for (int w = 0; w < wid; ++w) wprefix += ws[w];
  incl += wprefix;
  if (t < nb) bsum[t] = incl - v;          // exclusive
  if (t == nb - 1) rowptr[nfull] = incl;   // grand total
}

// ---------------------------------------------------------------------------
// Scan phase 3: in-place exclusive scan of counts using bsum offsets.
// counts buffer then serves as the scatter write-pointer.
// ---------------------------------------------------------------------------
__global__ __launch_bounds__(256) void scan_apply_kernel(
    int* __restrict__ counts, const int* __restrict__ bsum,
    int* __restrict__ rowptr, int n) {
  __shared__ int ws[4];
  int i = blockIdx.x * 256 + threadIdx.x;
  int lane = threadIdx.x & 63, wid = threadIdx.x >> 6;
  int v = (i < n) ? counts[i] : 0;
  int incl = v;
#pragma unroll
  for (int off = 1; off < 64; off <<= 1) {
    int u = __shfl_up(incl, off, 64);
    if (lane >= off) incl += u;
  }
  if (lane == 63) ws[wid] = incl;
  __syncthreads();
  int wprefix = 0;
  for (int w = 0; w < wid; ++w) wprefix += ws[w];
  int excl = bsum[blockIdx.x] + wprefix + (incl - v);
  if (i < n) { rowptr[i] = excl; counts[i] = excl; }
}

// ---------------------------------------------------------------------------
// XCD-partitioned packed scatter (one 8B {col,val} store per edge; all
// stores to a partition's slice come from one XCD's L2 -> sectors merge).
// ---------------------------------------------------------------------------
__global__ __launch_bounds__(256) void scatter_part_kernel(
    const int* __restrict__ row, const int* __restrict__ col,
    const float* __restrict__ val, int* __restrict__ wptr,
    int2* __restrict__ pairs, int e) {
  int part = blockIdx.x & (NPART - 1);
  int q    = blockIdx.x >> 3;
  int Q    = gridDim.x >> 3;
  int lo = part * RPP, hi = lo + RPP;
  for (int i = q * 256 + threadIdx.x; i < e; i += Q * 256) {
    int r = row[i];
    if (r >= lo && r < hi) {
      int p = atomicAdd(&wptr[r], 1);
      pairs[p] = make_int2(col[i], __float_as_int(val[i]));
    }
  }
}

// ---------------------------------------------------------------------------
// CSR SpMM, D=128. One 32-lane group per row, float4 per lane.
// 8-wide edge unroll: the previous version (VGPR_Count=12) kept exactly ONE
// dense gather in flight per row-group -> latency-bound at 3.3 TB/s.
// Batching 8 pair loads then 8 independent 512B gathers before the first
// consuming FMA raises per-wave MLP 8x; 4 accumulators break the FMA chain.
// ---------------------------------------------------------------------------
template <bool EPI>
__global__ __launch_bounds__(256) void spmm_kernel(
    const int* __restrict__ rowptr, const int2* __restrict__ pairs,
    const float* __restrict__ dense, const float* __restrict__ bias,
    float* __restrict__ out, int n) {
  int r = blockIdx.x * 8 + (threadIdx.x >> 5);
  if (r >= n) return;
  int c4 = (threadIdx.x & 31);  // float4 index within row
  const float4* dense4 = (const float4*)dense;
  int s = rowptr[r], e = rowptr[r + 1];
  float4 a0 = make_float4(0.f, 0.f, 0.f, 0.f);
  float4 a1 = a0, a2 = a0, a3 = a0;
  int j = s;
  for (; j + 8 <= e; j += 8) {
    int2 p0 = pairs[j + 0], p1 = pairs[j + 1], p2 = pairs[j + 2], p3 = pairs[j + 3];
    int2 p4 = pairs[j + 4], p5 = pairs[j + 5], p6 = pairs[j + 6], p7 = pairs[j + 7];
    float4 d0 = dense4[(size_t)p0.x * 32 + c4];
    float4 d1 = dense4[(size_t)p1.x * 32 + c4];
    float4 d2 = dense4[(size_t)p2.x * 32 + c4];
    float4 d3 = dense4[(size_t)p3.x * 32 + c4];
    float4 d4 = dense4[(size_t)p4.x * 32 + c4];
    float4 d5 = dense4[(size_t)p5.x * 32 + c4];
    float4 d6 = dense4[(size_t)p6.x * 32 + c4];
    float4 d7 = dense4[(size_t)p7.x * 32 + c4];
    fma4(a0, __int_as_float(p0.y), d0);
    fma4(a1, __int_as_float(p1.y), d1);
    fma4(a2, __int_as_float(p2.y), d2);
    fma4(a3, __int_as_float(p3.y), d3);
    fma4(a0, __int_as_float(p4.y), d4);
    fma4(a1, __int_as_float(p5.y), d5);
    fma4(a2, __int_as_float(p6.y), d6);
    fma4(a3, __int_as_float(p7.y), d7);
  }
  for (; j < e; ++j) {
    int2 ev = pairs[j];
    float4 d = dense4[(size_t)ev.x * 32 + c4];
    fma4(a0, __int_as_float(ev.y), d);
  }
  float4 acc;
  acc.x = (a0.x + a1.x) + (a2.x + a3.x);
  acc.y = (a0.y + a1.y) + (a2.y + a3.y);
  acc.z = (a0.z + a1.z) + (a2.z + a3.z);
  acc.w = (a0.w + a1.w) + (a2.w + a3.w);
  if (EPI) {
    float4 b = ((const float4*)bias)[c4];
    acc.x = fmaxf(acc.x + b.x, 0.f);
    acc.y = fmaxf(acc.y + b.y, 0.f);
    acc.z = fmaxf(acc.z + b.z, 0.f);
    acc.w = fmaxf(acc.w + b.w, 0.f);
  }
  *(float4*)(out + (size_t)r * 128 + c4 * 4) = acc;
}

// ---------------------------------------------------------------------------
// bf16-MFMA GEMM: C[M,N] = A[M,K]@B[K,N] (+bias,relu if EPI). fp32 in/out.
// 128x128 tile, BK=32, 256 thr = 4 waves (2x2), 16x16x32 MFMA, 4x4 tiles/wave.
// LDS holds bf16 fragments in fragment-major order: MFMA-side reads are
// linear ds_read_b128 (lane i -> byte i*16), conflict-free.
// ---------------------------------------------------------------------------
template <int K, int N, bool EPI>
__global__ __launch_bounds__(256) void gemm_mfma_kernel(
    const float* __restrict__ A, const float* __restrict__ B,
    const float* __restrict__ bias, float* __restrict__ C, int M) {
  __shared__ __align__(16) unsigned short Alds[4096];  // 128x32 bf16
  __shared__ __align__(16) unsigned short Blds[4096];  // 32x128 bf16
  int tid = threadIdx.x;
  int lane = tid & 63, wid = tid >> 6;
  int wm = wid >> 1, wn = wid & 1;          // 2x2 wave grid
  int rowBase = blockIdx.x * 128;
  int colBase = blockIdx.y * 128;
  // A staging coords: thread covers (m = p*32 + tid>>3, k = (tid&7)*4)
  int kg = tid & 7, mrow = tid >> 3;
  int aquad = kg >> 1, aj0 = (kg & 1) * 4;
  // B staging coords: thread covers (col = tid&127, k = p*8 + (tid>>7)*4)
  int bn = tid & 127, kh = tid >> 7;
  int NTb = bn >> 4, nloc = bn & 15;

  f32x4 acc[4][4];
#pragma unroll
  for (int mt = 0; mt < 4; ++mt)
#pragma unroll
    for (int nt = 0; nt < 4; ++nt)
      acc[mt][nt] = (f32x4){0.f, 0.f, 0.f, 0.f};

  for (int kb = 0; kb < K; kb += 32) {
    // ---- global loads (fp32) ----
    float4 av[4];
#pragma unroll
    for (int p = 0; p < 4; ++p) {
      int r = rowBase + p * 32 + mrow;
      av[p] = (r < M) ? *(const float4*)(A + (size_t)r * K + kb + kg * 4)
                      : make_float4(0.f, 0.f, 0.f, 0.f);
    }
    float bv[4][4];
#pragma unroll
    for (int p = 0; p < 4; ++p) {
      int k = p * 8 + kh * 4;
#pragma unroll
      for (int i = 0; i < 4; ++i)
        bv[p][i] = B[(size_t)(kb + k + i) * N + colBase + bn];
    }
    __syncthreads();  // previous iteration's LDS reads complete
    // ---- convert + LDS store (fragment-major) ----
#pragma unroll
    for (int p = 0; p < 4; ++p) {
      int m = p * 32 + mrow;
      int MT = m >> 4, mloc = m & 15;
      us4 h = {f2bf(av[p].x), f2bf(av[p].y), f2bf(av[p].z), f2bf(av[p].w)};
      *(us4*)&Alds[(((MT * 4 + aquad) * 16 + mloc) << 3) + aj0] = h;
    }
#pragma unroll
    for (int p = 0; p < 4; ++p) {
      us4 h = {f2bf(bv[p][0]), f2bf(bv[p][1]), f2bf(bv[p][2]), f2bf(bv[p][3])};
      *(us4*)&Blds[(((NTb * 4 + p) * 16 + nloc) << 3) + kh * 4] = h;
    }
    __syncthreads();
    // ---- MFMA ----
    bf16x8 af[4], bf[4];
#pragma unroll
    for (int mt = 0; mt < 4; ++mt)
      af[mt] = *(bf16x8*)&Alds[(((wm * 4 + mt) * 64 + lane)) << 3];
#pragma unroll
    for (int nt = 0; nt < 4; ++nt)
      bf[nt] = *(bf16x8*)&Blds[(((wn * 4 + nt) * 64 + lane)) << 3];
#pragma unroll
    for (int mt = 0; mt < 4; ++mt)
#pragma unroll
      for (int nt = 0; nt < 4; ++nt)
        acc[mt][nt] = __builtin_amdgcn_mfma_f32_16x16x32_bf16(
            af[mt], bf[nt], acc[mt][nt], 0, 0, 0);
  }
  // ---- epilogue: C/D layout col=lane&15, row=(lane>>4)*4+i ----
  int cquad = lane >> 4, cn = lane & 15;
#pragma unroll
  for (int nt = 0; nt < 4; ++nt) {
    int col = colBase + wn * 64 + nt * 16 + cn;
    float bb = EPI ? bias[col] : 0.f;
#pragma unroll
    for (int mt = 0; mt < 4; ++mt) {
      int r0 = rowBase + wm * 64 + mt * 16 + cquad * 4;
#pragma unroll
      for (int i = 0; i < 4; ++i) {
        int r = r0 + i;
        if (r < M) {
          float o = acc[mt][nt][i];
          if (EPI) o = fmaxf(o + bb, 0.f);
          C[(size_t)r * N + col] = o;
        }
      }
    }
  }
}

// ---------------------------------------------------------------------------
extern "C" void kernel_launch(void* const* d_in, const int* in_sizes, int n_in,
                              void* d_out, int out_size, void* d_ws, size_t ws_size,
                              hipStream_t stream) {
  const float* x        = (const float*)d_in[0];
  const int*   adj_row  = (const int*)d_in[1];
  const int*   adj_col  = (const int*)d_in[2];
  const float* adj_val  = (const float*)d_in[3];
  const int*   ainv_row = (const int*)d_in[4];
  const int*   ainv_col = (const int*)d_in[5];
  const float* ainv_val = (const float*)d_in[6];
  const float* W1       = (const float*)d_in[7];
  const float* b1       = (const float*)d_in[8];
  const float* W2       = (const float*)d_in[9];
  const float* b2       = (const float*)d_in[10];

  float* out = (float*)d_out;                    // [N,512]
  float* emb = out + (size_t)NN * NFEAT;         // [N,128]

  // Workspace carve (~52 MB)
  float* H0       = (float*)d_ws;                // [N,128]; later aliased as T
  int*   rowptr_a = (int*)(H0 + (size_t)NN * HIDD);
  int*   rowptr_b = rowptr_a + 50004;
  int*   wptr_a   = rowptr_b + 50004;            // histogram -> write ptr
  int*   wptr_b   = wptr_a + 50004;
  int*   bsum_a   = wptr_b + 50004;              // NB=196 partials
  int*   bsum_b   = bsum_a + 256;
  int2*  pairs_a  = (int2*)(bsum_b + 256);       // NE packed {col,val}
  int2*  pairs_b  = pairs_a + NE;
  float* T        = H0;  // alias: H0 dead by the time T is written

  // ---- CSR build for both graphs ----
  hipMemsetAsync(wptr_a, 0, NN * sizeof(int), stream);
  hipMemsetAsync(wptr_b, 0, NN * sizeof(int), stream);
  hist_kernel<<<NE / 256, 256, 0, stream>>>(adj_row, wptr_a, NE);
  hist_kernel<<<NE / 256, 256, 0, stream>>>(ainv_row, wptr_b, NE);
  block_sum_kernel<<<NB, 256, 0, stream>>>(wptr_a, bsum_a, NN);
  block_sum_kernel<<<NB, 256, 0, stream>>>(wptr_b, bsum_b, NN);
  scan_partials_kernel<<<1, 256, 0, stream>>>(bsum_a, rowptr_a, NB, NN);
  scan_partials_kernel<<<1, 256, 0, stream>>>(bsum_b, rowptr_b, NB, NN);
  scan_apply_kernel<<<NB, 256, 0, stream>>>(wptr_a, bsum_a, rowptr_a, NN);
  scan_apply_kernel<<<NB, 256, 0, stream>>>(wptr_b, bsum_b, rowptr_b, NN);
  scatter_part_kernel<<<2048, 256, 0, stream>>>(adj_row, adj_col, adj_val,
                                                wptr_a, pairs_a, NE);
  scatter_part_kernel<<<2048, 256, 0, stream>>>(ainv_row, ainv_col, ainv_val,
                                                wptr_b, pairs_b, NE);

  // ---- H0 = X @ W1 (bf16 MFMA) ----
  gemm_mfma_kernel<NFEAT, HIDD, false>
      <<<dim3((NN + 127) / 128, 1), 256, 0, stream>>>(x, W1, nullptr, H0, NN);

  // ---- emb = relu(A @ H0 + b1) ----
  spmm_kernel<true><<<(NN + 7) / 8, 256, 0, stream>>>(
      rowptr_a, pairs_a, H0, b1, emb, NN);

  // ---- T = A_inv @ emb  (reassociated: (A_inv @ h) @ W2) ----
  spmm_kernel<false><<<(NN + 7) / 8, 256, 0, stream>>>(
      rowptr_b, pairs_b, emb, nullptr, T, NN);

  // ---- out = relu(T @ W2 + b2) (bf16 MFMA) ----
  gemm_mfma_kernel<HIDD, NFEAT, true>
      <<<dim3((NN + 127) / 128, 4), 256, 0, stream>>>(T, W2, b2, out, NN);
}

// Round 3
// 711.348 us; speedup vs baseline: 1.1565x; 1.1373x over previous
//
#include <hip/hip_runtime.h>

// Problem constants (from reference)
#define NN     50000
#define NFEAT  512
#define HIDD   128
#define NE     1600000
#define NB     ((NN + 255) / 256)   // 196 blocks for per-node arrays
#define NPART  8                    // row partitions ~ XCDs
#define RPP    (NN / NPART)         // 6250 rows per partition

typedef __attribute__((ext_vector_type(8))) short    bf16x8;
typedef __attribute__((ext_vector_type(4))) float    f32x4;
typedef __attribute__((ext_vector_type(4))) unsigned short us4;

__device__ inline unsigned short f2bf(float f) {   // fp32 -> bf16 RNE
  unsigned int u = __float_as_uint(f);
  u += 0x7FFFu + ((u >> 16) & 1u);
  return (unsigned short)(u >> 16);
}

__device__ inline float bf2f(unsigned short h) {   // bf16 -> fp32
  return __uint_as_float((unsigned int)h << 16);
}

__device__ inline void fma4(float4& a, float v, const float4& d) {
  a.x = fmaf(v, d.x, a.x);
  a.y = fmaf(v, d.y, a.y);
  a.z = fmaf(v, d.z, a.z);
  a.w = fmaf(v, d.w, a.w);
}

__device__ inline void fma4b(float4& a, float v, us4 d) {
  a.x = fmaf(v, bf2f(d[0]), a.x);
  a.y = fmaf(v, bf2f(d[1]), a.y);
  a.z = fmaf(v, bf2f(d[2]), a.z);
  a.w = fmaf(v, bf2f(d[3]), a.w);
}

// ---------------------------------------------------------------------------
// Histogram: counts[row[i]]++  (int atomics)
// ---------------------------------------------------------------------------
__global__ __launch_bounds__(256) void hist_kernel(
    const int* __restrict__ row, int* __restrict__ counts, int e) {
  int i = blockIdx.x * blockDim.x + threadIdx.x;
  if (i < e) atomicAdd(&counts[row[i]], 1);
}

// ---------------------------------------------------------------------------
// Scan phase 1: per-block sums of counts -> bsum[block]
// ---------------------------------------------------------------------------
__global__ __launch_bounds__(256) void block_sum_kernel(
    const int* __restrict__ counts, int* __restrict__ bsum, int n) {
  __shared__ int ws[4];
  int i = blockIdx.x * 256 + threadIdx.x;
  int lane = threadIdx.x & 63, wid = threadIdx.x >> 6;
  int v = (i < n) ? counts[i] : 0;
#pragma unroll
  for (int off = 32; off > 0; off >>= 1) v += __shfl_down(v, off, 64);
  if (lane == 0) ws[wid] = v;
  __syncthreads();
  if (threadIdx.x == 0) bsum[blockIdx.x] = ws[0] + ws[1] + ws[2] + ws[3];
}

// ---------------------------------------------------------------------------
// Scan phase 2: single block, exclusive-scan nb partials in place;
// write grand total to rowptr[NN].
// ---------------------------------------------------------------------------
__global__ __launch_bounds__(256) void scan_partials_kernel(
    int* __restrict__ bsum, int* __restrict__ rowptr, int nb, int nfull) {
  __shared__ int ws[4];
  int t = threadIdx.x;
  int lane = t & 63, wid = t >> 6;
  int v = (t < nb) ? bsum[t] : 0;
  int incl = v;
#pragma unroll
  for (int off = 1; off < 64; off <<= 1) {
    int u = __shfl_up(incl, off, 64);
    if (lane >= off) incl += u;
  }
  if (lane == 63) ws[wid] = incl;
  __syncthreads();
  int wprefix = 0;
  for (int w = 0; w < wid; ++w) wprefix += ws[w];
  incl += wprefix;
  if (t < nb) bsum[t] = incl - v;          // exclusive
  if (t == nb - 1) rowptr[nfull] = incl;   // grand total
}

// ---------------------------------------------------------------------------
// Scan phase 3: in-place exclusive scan of counts using bsum offsets.
// counts buffer then serves as the scatter write-pointer.
// ---------------------------------------------------------------------------
__global__ __launch_bounds__(256) void scan_apply_kernel(
    int* __restrict__ counts, const int* __restrict__ bsum,
    int* __restrict__ rowptr, int n) {
  __shared__ int ws[4];
  int i = blockIdx.x * 256 + threadIdx.x;
  int lane = threadIdx.x & 63, wid = threadIdx.x >> 6;
  int v = (i < n) ? counts[i] : 0;
  int incl = v;
#pragma unroll
  for (int off = 1; off < 64; off <<= 1) {
    int u = __shfl_up(incl, off, 64);
    if (lane >= off) incl += u;
  }
  if (lane == 63) ws[wid] = incl;
  __syncthreads();
  int wprefix = 0;
  for (int w = 0; w < wid; ++w) wprefix += ws[w];
  int excl = bsum[blockIdx.x] + wprefix + (incl - v);
  if (i < n) { rowptr[i] = excl; counts[i] = excl; }
}

// ---------------------------------------------------------------------------
// XCD-partitioned packed scatter (one 8B {col,val} store per edge; all
// stores to a partition's slice come from one XCD's L2 -> sectors merge).
// ---------------------------------------------------------------------------
__global__ __launch_bounds__(256) void scatter_part_kernel(
    const int* __restrict__ row, const int* __restrict__ col,
    const float* __restrict__ val, int* __restrict__ wptr,
    int2* __restrict__ pairs, int e) {
  int part = blockIdx.x & (NPART - 1);
  int q    = blockIdx.x >> 3;
  int Q    = gridDim.x >> 3;
  int lo = part * RPP, hi = lo + RPP;
  for (int i = q * 256 + threadIdx.x; i < e; i += Q * 256) {
    int r = row[i];
    if (r >= lo && r < hi) {
      int p = atomicAdd(&wptr[r], 1);
      pairs[p] = make_int2(col[i], __float_as_int(val[i]));
    }
  }
}

// ---------------------------------------------------------------------------
// CSR SpMM, D=128. One 32-lane group per row, 8-wide edge unroll.
// Round-2 revision: beyond-L2 gather stream saturates ~3.6 TB/s on fp32
// (356 MB beyond-L2 per dispatch); MLP is no longer the limit. bf16 dense
// (DB16) halves gather bytes AND halves the footprint (25.6->12.8 MB) so
// per-XCD L2 hit rate rises -> fewer beyond-L2 bytes at the same stream rate.
// Outputs: optional fp32 (WF32, exact result) and/or bf16 copy (WB16) for
// the next consumer's gather/GEMM (which bf16-rounds anyway).
// ---------------------------------------------------------------------------
template <bool DB16, bool EPI, bool WF32, bool WB16>
__global__ __launch_bounds__(256) void spmm_kernel(
    const int* __restrict__ rowptr, const int2* __restrict__ pairs,
    const void* __restrict__ dense, const float* __restrict__ bias,
    float* __restrict__ outf, unsigned short* __restrict__ outb, int n) {
  int r = blockIdx.x * 8 + (threadIdx.x >> 5);
  if (r >= n) return;
  int c4 = (threadIdx.x & 31);  // 4-feature chunk index within row
  int s = rowptr[r], e = rowptr[r + 1];
  float4 a0 = make_float4(0.f, 0.f, 0.f, 0.f);
  float4 a1 = a0, a2 = a0, a3 = a0;
  int j = s;
  if constexpr (DB16) {
    const unsigned short* d16 = (const unsigned short*)dense;
    for (; j + 8 <= e; j += 8) {
      int2 p0 = pairs[j + 0], p1 = pairs[j + 1], p2 = pairs[j + 2], p3 = pairs[j + 3];
      int2 p4 = pairs[j + 4], p5 = pairs[j + 5], p6 = pairs[j + 6], p7 = pairs[j + 7];
      us4 d0 = *(const us4*)(d16 + (size_t)p0.x * 128 + c4 * 4);
      us4 d1 = *(const us4*)(d16 + (size_t)p1.x * 128 + c4 * 4);
      us4 d2 = *(const us4*)(d16 + (size_t)p2.x * 128 + c4 * 4);
      us4 d3 = *(const us4*)(d16 + (size_t)p3.x * 128 + c4 * 4);
      us4 d4 = *(const us4*)(d16 + (size_t)p4.x * 128 + c4 * 4);
      us4 d5 = *(const us4*)(d16 + (size_t)p5.x * 128 + c4 * 4);
      us4 d6 = *(const us4*)(d16 + (size_t)p6.x * 128 + c4 * 4);
      us4 d7 = *(const us4*)(d16 + (size_t)p7.x * 128 + c4 * 4);
      fma4b(a0, __int_as_float(p0.y), d0);
      fma4b(a1, __int_as_float(p1.y), d1);
      fma4b(a2, __int_as_float(p2.y), d2);
      fma4b(a3, __int_as_float(p3.y), d3);
      fma4b(a0, __int_as_float(p4.y), d4);
      fma4b(a1, __int_as_float(p5.y), d5);
      fma4b(a2, __int_as_float(p6.y), d6);
      fma4b(a3, __int_as_float(p7.y), d7);
    }
    for (; j < e; ++j) {
      int2 ev = pairs[j];
      us4 d = *(const us4*)(d16 + (size_t)ev.x * 128 + c4 * 4);
      fma4b(a0, __int_as_float(ev.y), d);
    }
  } else {
    const float4* dense4 = (const float4*)dense;
    for (; j + 8 <= e; j += 8) {
      int2 p0 = pairs[j + 0], p1 = pairs[j + 1], p2 = pairs[j + 2], p3 = pairs[j + 3];
      int2 p4 = pairs[j + 4], p5 = pairs[j + 5], p6 = pairs[j + 6], p7 = pairs[j + 7];
      float4 d0 = dense4[(size_t)p0.x * 32 + c4];
      float4 d1 = dense4[(size_t)p1.x * 32 + c4];
      float4 d2 = dense4[(size_t)p2.x * 32 + c4];
      float4 d3 = dense4[(size_t)p3.x * 32 + c4];
      float4 d4 = dense4[(size_t)p4.x * 32 + c4];
      float4 d5 = dense4[(size_t)p5.x * 32 + c4];
      float4 d6 = dense4[(size_t)p6.x * 32 + c4];
      float4 d7 = dense4[(size_t)p7.x * 32 + c4];
      fma4(a0, __int_as_float(p0.y), d0);
      fma4(a1, __int_as_float(p1.y), d1);
      fma4(a2, __int_as_float(p2.y), d2);
      fma4(a3, __int_as_float(p3.y), d3);
      fma4(a0, __int_as_float(p4.y), d4);
      fma4(a1, __int_as_float(p5.y), d5);
      fma4(a2, __int_as_float(p6.y), d6);
      fma4(a3, __int_as_float(p7.y), d7);
    }
    for (; j < e; ++j) {
      int2 ev = pairs[j];
      float4 d = dense4[(size_t)ev.x * 32 + c4];
      fma4(a0, __int_as_float(ev.y), d);
    }
  }
  float4 acc;
  acc.x = (a0.x + a1.x) + (a2.x + a3.x);
  acc.y = (a0.y + a1.y) + (a2.y + a3.y);
  acc.z = (a0.z + a1.z) + (a2.z + a3.z);
  acc.w = (a0.w + a1.w) + (a2.w + a3.w);
  if (EPI) {
    float4 b = ((const float4*)bias)[c4];
    acc.x = fmaxf(acc.x + b.x, 0.f);
    acc.y = fmaxf(acc.y + b.y, 0.f);
    acc.z = fmaxf(acc.z + b.z, 0.f);
    acc.w = fmaxf(acc.w + b.w, 0.f);
  }
  if (WF32)
    *(float4*)(outf + (size_t)r * 128 + c4 * 4) = acc;
  if (WB16) {
    us4 h = {f2bf(acc.x), f2bf(acc.y), f2bf(acc.z), f2bf(acc.w)};
    *(us4*)(outb + (size_t)r * 128 + c4 * 4) = h;
  }
}

// ---------------------------------------------------------------------------
// bf16-MFMA GEMM: C[M,N] = A[M,K]@B[K,N] (+bias,relu if EPI). B fp32.
// A fp32 (converted during staging) or bf16 (ABF16 - staged directly).
// C fp32 or bf16 (OUTB). 128x128 tile, BK=32, 4 waves, 16x16x32 MFMA.
// LDS fragment-major: MFMA-side reads are linear ds_read_b128, conflict-free.
// ---------------------------------------------------------------------------
template <int K, int N, bool EPI, bool ABF16, bool OUTB>
__global__ __launch_bounds__(256) void gemm_mfma_kernel(
    const void* __restrict__ Av, const float* __restrict__ B,
    const float* __restrict__ bias, void* __restrict__ Cv, int M) {
  __shared__ __align__(16) unsigned short Alds[4096];  // 128x32 bf16
  __shared__ __align__(16) unsigned short Blds[4096];  // 32x128 bf16
  int tid = threadIdx.x;
  int lane = tid & 63, wid = tid >> 6;
  int wm = wid >> 1, wn = wid & 1;          // 2x2 wave grid
  int rowBase = blockIdx.x * 128;
  int colBase = blockIdx.y * 128;
  // A staging coords: thread covers (m = p*32 + tid>>3, k = (tid&7)*4)
  int kg = tid & 7, mrow = tid >> 3;
  int aquad = kg >> 1, aj0 = (kg & 1) * 4;
  // B staging coords: thread covers (col = tid&127, k = p*8 + (tid>>7)*4)
  int bn = tid & 127, kh = tid >> 7;
  int NTb = bn >> 4, nloc = bn & 15;

  f32x4 acc[4][4];
#pragma unroll
  for (int mt = 0; mt < 4; ++mt)
#pragma unroll
    for (int nt = 0; nt < 4; ++nt)
      acc[mt][nt] = (f32x4){0.f, 0.f, 0.f, 0.f};

  for (int kb = 0; kb < K; kb += 32) {
    // ---- global loads ----
    float4 av[4];
    us4 av16[4];
    if constexpr (ABF16) {
      const unsigned short* A = (const unsigned short*)Av;
#pragma unroll
      for (int p = 0; p < 4; ++p) {
        int r = rowBase + p * 32 + mrow;
        av16[p] = (r < M) ? *(const us4*)(A + (size_t)r * K + kb + kg * 4)
                          : (us4){0, 0, 0, 0};
      }
    } else {
      const float* A = (const float*)Av;
#pragma unroll
      for (int p = 0; p < 4; ++p) {
        int r = rowBase + p * 32 + mrow;
        av[p] = (r < M) ? *(const float4*)(A + (size_t)r * K + kb + kg * 4)
                        : make_float4(0.f, 0.f, 0.f, 0.f);
      }
    }
    float bv[4][4];
#pragma unroll
    for (int p = 0; p < 4; ++p) {
      int k = p * 8 + kh * 4;
#pragma unroll
      for (int i = 0; i < 4; ++i)
        bv[p][i] = B[(size_t)(kb + k + i) * N + colBase + bn];
    }
    __syncthreads();  // previous iteration's LDS reads complete
    // ---- convert + LDS store (fragment-major) ----
#pragma unroll
    for (int p = 0; p < 4; ++p) {
      int m = p * 32 + mrow;
      int MT = m >> 4, mloc = m & 15;
      us4 h;
      if constexpr (ABF16) h = av16[p];
      else h = (us4){f2bf(av[p].x), f2bf(av[p].y), f2bf(av[p].z), f2bf(av[p].w)};
      *(us4*)&Alds[(((MT * 4 + aquad) * 16 + mloc) << 3) + aj0] = h;
    }
#pragma unroll
    for (int p = 0; p < 4; ++p) {
      us4 h = {f2bf(bv[p][0]), f2bf(bv[p][1]), f2bf(bv[p][2]), f2bf(bv[p][3])};
      *(us4*)&Blds[(((NTb * 4 + p) * 16 + nloc) << 3) + kh * 4] = h;
    }
    __syncthreads();
    // ---- MFMA ----
    bf16x8 af[4], bf[4];
#pragma unroll
    for (int mt = 0; mt < 4; ++mt)
      af[mt] = *(bf16x8*)&Alds[(((wm * 4 + mt) * 64 + lane)) << 3];
#pragma unroll
    for (int nt = 0; nt < 4; ++nt)
      bf[nt] = *(bf16x8*)&Blds[(((wn * 4 + nt) * 64 + lane)) << 3];
#pragma unroll
    for (int mt = 0; mt < 4; ++mt)
#pragma unroll
      for (int nt = 0; nt < 4; ++nt)
        acc[mt][nt] = __builtin_amdgcn_mfma_f32_16x16x32_bf16(
            af[mt], bf[nt], acc[mt][nt], 0, 0, 0);
  }
  // ---- epilogue: C/D layout col=lane&15, row=(lane>>4)*4+i ----
  int cquad = lane >> 4, cn = lane & 15;
#pragma unroll
  for (int nt = 0; nt < 4; ++nt) {
    int col = colBase + wn * 64 + nt * 16 + cn;
    float bb = EPI ? bias[col] : 0.f;
#pragma unroll
    for (int mt = 0; mt < 4; ++mt) {
      int r0 = rowBase + wm * 64 + mt * 16 + cquad * 4;
#pragma unroll
      for (int i = 0; i < 4; ++i) {
        int r = r0 + i;
        if (r < M) {
          float o = acc[mt][nt][i];
          if (EPI) o = fmaxf(o + bb, 0.f);
          if constexpr (OUTB)
            ((unsigned short*)Cv)[(size_t)r * N + col] = f2bf(o);
          else
            ((float*)Cv)[(size_t)r * N + col] = o;
        }
      }
    }
  }
}

// ---------------------------------------------------------------------------
extern "C" void kernel_launch(void* const* d_in, const int* in_sizes, int n_in,
                              void* d_out, int out_size, void* d_ws, size_t ws_size,
                              hipStream_t stream) {
  const float* x        = (const float*)d_in[0];
  const int*   adj_row  = (const int*)d_in[1];
  const int*   adj_col  = (const int*)d_in[2];
  const float* adj_val  = (const float*)d_in[3];
  const int*   ainv_row = (const int*)d_in[4];
  const int*   ainv_col = (const int*)d_in[5];
  const float* ainv_val = (const float*)d_in[6];
  const float* W1       = (const float*)d_in[7];
  const float* b1       = (const float*)d_in[8];
  const float* W2       = (const float*)d_in[9];
  const float* b2       = (const float*)d_in[10];

  float* out = (float*)d_out;                    // [N,512]
  float* emb = out + (size_t)NN * NFEAT;         // [N,128] (fp32 output)

  // Workspace carve (256B-aligned chunks)
  size_t off = 0;
  auto carve = [&](size_t bytes) {
    void* p = (char*)d_ws + off;
    off += (bytes + 255) & ~(size_t)255;
    return p;
  };
  unsigned short* Tb   = (unsigned short*)carve((size_t)NN * HIDD * 2);  // 12.8MB
  unsigned short* H0b  = (unsigned short*)carve((size_t)NN * HIDD * 2);  // 12.8MB
  int*  rowptr_a = (int*)carve(50004 * 4);
  int*  rowptr_b = (int*)carve(50004 * 4);
  int*  wptr_a   = (int*)carve(50004 * 4);
  int*  wptr_b   = (int*)carve(50004 * 4);
  int*  bsum_a   = (int*)carve(256 * 4);
  int*  bsum_b   = (int*)carve(256 * 4);
  int2* pairs_a  = (int2*)carve((size_t)NE * 8);                          // 12.8MB
  int2* pairs_b  = (int2*)carve((size_t)NE * 8);                          // 12.8MB
  // Optional bf16 copy of emb for spmm2's gather (+12.8MB) — only if ws fits.
  unsigned short* embb = (unsigned short*)((char*)d_ws + off);
  bool full = ws_size >= off + (size_t)NN * HIDD * 2;

  // ---- CSR build for both graphs ----
  hipMemsetAsync(wptr_a, 0, NN * sizeof(int), stream);
  hipMemsetAsync(wptr_b, 0, NN * sizeof(int), stream);
  hist_kernel<<<NE / 256, 256, 0, stream>>>(adj_row, wptr_a, NE);
  hist_kernel<<<NE / 256, 256, 0, stream>>>(ainv_row, wptr_b, NE);
  block_sum_kernel<<<NB, 256, 0, stream>>>(wptr_a, bsum_a, NN);
  block_sum_kernel<<<NB, 256, 0, stream>>>(wptr_b, bsum_b, NN);
  scan_partials_kernel<<<1, 256, 0, stream>>>(bsum_a, rowptr_a, NB, NN);
  scan_partials_kernel<<<1, 256, 0, stream>>>(bsum_b, rowptr_b, NB, NN);
  scan_apply_kernel<<<NB, 256, 0, stream>>>(wptr_a, bsum_a, rowptr_a, NN);
  scan_apply_kernel<<<NB, 256, 0, stream>>>(wptr_b, bsum_b, rowptr_b, NN);
  scatter_part_kernel<<<2048, 256, 0, stream>>>(adj_row, adj_col, adj_val,
                                                wptr_a, pairs_a, NE);
  scatter_part_kernel<<<2048, 256, 0, stream>>>(ainv_row, ainv_col, ainv_val,
                                                wptr_b, pairs_b, NE);

  // ---- H0b = bf16(X @ W1) (bf16 MFMA, bf16 out) ----
  gemm_mfma_kernel<NFEAT, HIDD, false, false, true>
      <<<dim3((NN + 127) / 128, 1), 256, 0, stream>>>(x, W1, nullptr, H0b, NN);

  // ---- emb = relu(A @ H0 + b1); also bf16 copy for next gather ----
  if (full)
    spmm_kernel<true, true, true, true><<<(NN + 7) / 8, 256, 0, stream>>>(
        rowptr_a, pairs_a, H0b, b1, emb, embb, NN);
  else
    spmm_kernel<true, true, true, false><<<(NN + 7) / 8, 256, 0, stream>>>(
        rowptr_a, pairs_a, H0b, b1, emb, nullptr, NN);

  // ---- Tb = bf16(A_inv @ emb)  (reassociated: (A_inv @ h) @ W2) ----
  // T was bf16-rounded inside GEMM2's staging anyway -> no extra loss here.
  if (full)
    spmm_kernel<true, false, false, true><<<(NN + 7) / 8, 256, 0, stream>>>(
        rowptr_b, pairs_b, embb, nullptr, nullptr, Tb, NN);
  else
    spmm_kernel<false, false, false, true><<<(NN + 7) / 8, 256, 0, stream>>>(
        rowptr_b, pairs_b, emb, nullptr, nullptr, Tb, NN);

  // ---- out = relu(Tb @ W2 + b2) (bf16 MFMA, bf16 A operand) ----
  gemm_mfma_kernel<HIDD, NFEAT, true, true, false>
      <<<dim3((NN + 127) / 128, 4), 256, 0, stream>>>(Tb, W2, b2, out, NN);
}

// Round 5
// 684.606 us; speedup vs baseline: 1.2016x; 1.0391x over previous
//
#include <hip/hip_runtime.h>

// Problem constants (from reference)
#define NN     50000
#define NFEAT  512
#define HIDD   128
#define NE     1600000
#define NB     ((NN + 255) / 256)   // 196 blocks for per-node arrays

typedef __attribute__((ext_vector_type(8))) short    bf16x8;
typedef __attribute__((ext_vector_type(4))) float    f32x4;
typedef __attribute__((ext_vector_type(4))) unsigned short us4;

__device__ inline unsigned short f2bf(float f) {   // fp32 -> bf16 RNE
  unsigned int u = __float_as_uint(f);
  u += 0x7FFFu + ((u >> 16) & 1u);
  return (unsigned short)(u >> 16);
}

__device__ inline float bf2f(unsigned short h) {   // bf16 -> fp32
  return __uint_as_float((unsigned int)h << 16);
}

__device__ inline void fma4(float4& a, float v, const float4& d) {
  a.x = fmaf(v, d.x, a.x);
  a.y = fmaf(v, d.y, a.y);
  a.z = fmaf(v, d.z, a.z);
  a.w = fmaf(v, d.w, a.w);
}

__device__ inline void fma4b(float4& a, float v, us4 d) {
  a.x = fmaf(v, bf2f(d[0]), a.x);
  a.y = fmaf(v, bf2f(d[1]), a.y);
  a.z = fmaf(v, bf2f(d[2]), a.z);
  a.w = fmaf(v, bf2f(d[3]), a.w);
}

// ---------------------------------------------------------------------------
// Hist + rank: rank[i] = old count of row[i]. The atomic return value IS the
// edge's within-row position, so the later scatter needs NO cursor atomics.
// Both graphs in one launch (blockIdx.y selects).
// ---------------------------------------------------------------------------
__global__ __launch_bounds__(256) void hist_rank_kernel(
    const int* __restrict__ rowA, const int* __restrict__ rowB,
    int* __restrict__ cntA, int* __restrict__ cntB,
    int* __restrict__ rnkA, int* __restrict__ rnkB, int e) {
  const int* row = blockIdx.y ? rowB : rowA;
  int*       cnt = blockIdx.y ? cntB : cntA;
  int*       rnk = blockIdx.y ? rnkB : rnkA;
  int i = blockIdx.x * 256 + threadIdx.x;
  if (i < e) rnk[i] = atomicAdd(&cnt[row[i]], 1);
}

// ---------------------------------------------------------------------------
// Scan phase 1: per-block sums of counts -> bsum[block]  (both graphs)
// ---------------------------------------------------------------------------
__global__ __launch_bounds__(256) void block_sum_kernel(
    const int* __restrict__ cntA, const int* __restrict__ cntB,
    int* __restrict__ bsumA, int* __restrict__ bsumB, int n) {
  const int* counts = blockIdx.y ? cntB : cntA;
  int*       bsum   = blockIdx.y ? bsumB : bsumA;
  __shared__ int ws[4];
  int i = blockIdx.x * 256 + threadIdx.x;
  int lane = threadIdx.x & 63, wid = threadIdx.x >> 6;
  int v = (i < n) ? counts[i] : 0;
#pragma unroll
  for (int off = 32; off > 0; off >>= 1) v += __shfl_down(v, off, 64);
  if (lane == 0) ws[wid] = v;
  __syncthreads();
  if (threadIdx.x == 0) bsum[blockIdx.x] = ws[0] + ws[1] + ws[2] + ws[3];
}

// ---------------------------------------------------------------------------
// Scan phase 2: one block per graph, exclusive-scan nb partials in place;
// write grand total to rowptr[NN].
// ---------------------------------------------------------------------------
__global__ __launch_bounds__(256) void scan_partials_kernel(
    int* __restrict__ bsumA, int* __restrict__ bsumB,
    int* __restrict__ rpA, int* __restrict__ rpB, int nb, int nfull) {
  int* bsum   = blockIdx.x ? bsumB : bsumA;
  int* rowptr = blockIdx.x ? rpB : rpA;
  __shared__ int ws[4];
  int t = threadIdx.x;
  int lane = t & 63, wid = t >> 6;
  int v = (t < nb) ? bsum[t] : 0;
  int incl = v;
#pragma unroll
  for (int off = 1; off < 64; off <<= 1) {
    int u = __shfl_up(incl, off, 64);
    if (lane >= off) incl += u;
  }
  if (lane == 63) ws[wid] = incl;
  __syncthreads();
  int wprefix = 0;
  for (int w = 0; w < wid; ++w) wprefix += ws[w];
  incl += wprefix;
  if (t < nb) bsum[t] = incl - v;          // exclusive
  if (t == nb - 1) rowptr[nfull] = incl;   // grand total
}

// ---------------------------------------------------------------------------
// Scan phase 3: exclusive scan of counts using bsum offsets -> rowptr.
// (counts no longer double as a scatter cursor — rank covers that.)
// ---------------------------------------------------------------------------
__global__ __launch_bounds__(256) void scan_apply_kernel(
    const int* __restrict__ cntA, const int* __restrict__ cntB,
    const int* __restrict__ bsumA, const int* __restrict__ bsumB,
    int* __restrict__ rpA, int* __restrict__ rpB, int n) {
  const int* counts = blockIdx.y ? cntB : cntA;
  const int* bsum   = blockIdx.y ? bsumB : bsumA;
  int*       rowptr = blockIdx.y ? rpB : rpA;
  __shared__ int ws[4];
  int i = blockIdx.x * 256 + threadIdx.x;
  int lane = threadIdx.x & 63, wid = threadIdx.x >> 6;
  int v = (i < n) ? counts[i] : 0;
  int incl = v;
#pragma unroll
  for (int off = 1; off < 64; off <<= 1) {
    int u = __shfl_up(incl, off, 64);
    if (lane >= off) incl += u;
  }
  if (lane == 63) ws[wid] = incl;
  __syncthreads();
  int wprefix = 0;
  for (int w = 0; w < wid; ++w) wprefix += ws[w];
  if (i < n) rowptr[i] = bsum[blockIdx.x] + wprefix + (incl - v);
}

// ---------------------------------------------------------------------------
// Rank-based scatter: p = rowptr[row[i]] + rank[i]. Single coalesced pass,
// zero cursor atomics. Pair store is a fire-and-forget 8B atomicExch:
// device-scope, merged memory-side, so cross-XCD shared-line write-back
// races cannot occur regardless of workgroup->XCD mapping.
// ---------------------------------------------------------------------------
__global__ __launch_bounds__(256) void scatter_rank_kernel(
    const int* __restrict__ rowA, const int* __restrict__ colA,
    const float* __restrict__ valA, const int* __restrict__ rnkA,
    const int* __restrict__ rpA, int2* __restrict__ pairsA,
    const int* __restrict__ rowB, const int* __restrict__ colB,
    const float* __restrict__ valB, const int* __restrict__ rnkB,
    const int* __restrict__ rpB, int2* __restrict__ pairsB, int e) {
  const int*   row   = blockIdx.y ? rowB : rowA;
  const int*   col   = blockIdx.y ? colB : colA;
  const float* val   = blockIdx.y ? valB : valA;
  const int*   rnk   = blockIdx.y ? rnkB : rnkA;
  const int*   rp    = blockIdx.y ? rpB : rpA;
  int2*        pairs = blockIdx.y ? pairsB : pairsA;
  int i = blockIdx.x * 256 + threadIdx.x;
  if (i < e) {
    int p = rp[row[i]] + rnk[i];
    unsigned long long v =
        (unsigned long long)(unsigned int)col[i] |
        ((unsigned long long)(unsigned int)__float_as_uint(val[i]) << 32);
    atomicExch((unsigned long long*)&pairs[p], v);  // no-return: pure store
  }
}

// ---------------------------------------------------------------------------
// CSR SpMM, D=128. One 32-lane group per row, 8-wide edge unroll.
// bf16 dense (DB16) halves gather bytes AND footprint (25.6->12.8 MB).
// Outputs: optional fp32 (WF32) and/or bf16 copy (WB16) for next consumer.
// ---------------------------------------------------------------------------
template <bool DB16, bool EPI, bool WF32, bool WB16>
__global__ __launch_bounds__(256) void spmm_kernel(
    const int* __restrict__ rowptr, const int2* __restrict__ pairs,
    const void* __restrict__ dense, const float* __restrict__ bias,
    float* __restrict__ outf, unsigned short* __restrict__ outb, int n) {
  int r = blockIdx.x * 8 + (threadIdx.x >> 5);
  if (r >= n) return;
  int c4 = (threadIdx.x & 31);  // 4-feature chunk index within row
  int s = rowptr[r], e = rowptr[r + 1];
  float4 a0 = make_float4(0.f, 0.f, 0.f, 0.f);
  float4 a1 = a0, a2 = a0, a3 = a0;
  int j = s;
  if constexpr (DB16) {
    const unsigned short* d16 = (const unsigned short*)dense;
    for (; j + 8 <= e; j += 8) {
      int2 p0 = pairs[j + 0], p1 = pairs[j + 1], p2 = pairs[j + 2], p3 = pairs[j + 3];
      int2 p4 = pairs[j + 4], p5 = pairs[j + 5], p6 = pairs[j + 6], p7 = pairs[j + 7];
      us4 d0 = *(const us4*)(d16 + (size_t)p0.x * 128 + c4 * 4);
      us4 d1 = *(const us4*)(d16 + (size_t)p1.x * 128 + c4 * 4);
      us4 d2 = *(const us4*)(d16 + (size_t)p2.x * 128 + c4 * 4);
      us4 d3 = *(const us4*)(d16 + (size_t)p3.x * 128 + c4 * 4);
      us4 d4 = *(const us4*)(d16 + (size_t)p4.x * 128 + c4 * 4);
      us4 d5 = *(const us4*)(d16 + (size_t)p5.x * 128 + c4 * 4);
      us4 d6 = *(const us4*)(d16 + (size_t)p6.x * 128 + c4 * 4);
      us4 d7 = *(const us4*)(d16 + (size_t)p7.x * 128 + c4 * 4);
      fma4b(a0, __int_as_float(p0.y), d0);
      fma4b(a1, __int_as_float(p1.y), d1);
      fma4b(a2, __int_as_float(p2.y), d2);
      fma4b(a3, __int_as_float(p3.y), d3);
      fma4b(a0, __int_as_float(p4.y), d4);
      fma4b(a1, __int_as_float(p5.y), d5);
      fma4b(a2, __int_as_float(p6.y), d6);
      fma4b(a3, __int_as_float(p7.y), d7);
    }
    for (; j < e; ++j) {
      int2 ev = pairs[j];
      us4 d = *(const us4*)(d16 + (size_t)ev.x * 128 + c4 * 4);
      fma4b(a0, __int_as_float(ev.y), d);
    }
  } else {
    const float4* dense4 = (const float4*)dense;
    for (; j + 8 <= e; j += 8) {
      int2 p0 = pairs[j + 0], p1 = pairs[j + 1], p2 = pairs[j + 2], p3 = pairs[j + 3];
      int2 p4 = pairs[j + 4], p5 = pairs[j + 5], p6 = pairs[j + 6], p7 = pairs[j + 7];
      float4 d0 = dense4[(size_t)p0.x * 32 + c4];
      float4 d1 = dense4[(size_t)p1.x * 32 + c4];
      float4 d2 = dense4[(size_t)p2.x * 32 + c4];
      float4 d3 = dense4[(size_t)p3.x * 32 + c4];
      float4 d4 = dense4[(size_t)p4.x * 32 + c4];
      float4 d5 = dense4[(size_t)p5.x * 32 + c4];
      float4 d6 = dense4[(size_t)p6.x * 32 + c4];
      float4 d7 = dense4[(size_t)p7.x * 32 + c4];
      fma4(a0, __int_as_float(p0.y), d0);
      fma4(a1, __int_as_float(p1.y), d1);
      fma4(a2, __int_as_float(p2.y), d2);
      fma4(a3, __int_as_float(p3.y), d3);
      fma4(a0, __int_as_float(p4.y), d4);
      fma4(a1, __int_as_float(p5.y), d5);
      fma4(a2, __int_as_float(p6.y), d6);
      fma4(a3, __int_as_float(p7.y), d7);
    }
    for (; j < e; ++j) {
      int2 ev = pairs[j];
      float4 d = dense4[(size_t)ev.x * 32 + c4];
      fma4(a0, __int_as_float(ev.y), d);
    }
  }
  float4 acc;
  acc.x = (a0.x + a1.x) + (a2.x + a3.x);
  acc.y = (a0.y + a1.y) + (a2.y + a3.y);
  acc.z = (a0.z + a1.z) + (a2.z + a3.z);
  acc.w = (a0.w + a1.w) + (a2.w + a3.w);
  if (EPI) {
    float4 b = ((const float4*)bias)[c4];
    acc.x = fmaxf(acc.x + b.x, 0.f);
    acc.y = fmaxf(acc.y + b.y, 0.f);
    acc.z = fmaxf(acc.z + b.z, 0.f);
    acc.w = fmaxf(acc.w + b.w, 0.f);
  }
  if (WF32)
    *(float4*)(outf + (size_t)r * 128 + c4 * 4) = acc;
  if (WB16) {
    us4 h = {f2bf(acc.x), f2bf(acc.y), f2bf(acc.z), f2bf(acc.w)};
    *(us4*)(outb + (size_t)r * 128 + c4 * 4) = h;
  }
}

// ---------------------------------------------------------------------------
// bf16-MFMA GEMM: C[M,N] = A[M,K]@B[K,N] (+bias,relu if EPI). B fp32.
// A fp32 (converted during staging) or bf16 (ABF16 - staged directly).
// C fp32 or bf16 (OUTB). 128x128 tile, BK=32, 4 waves, 16x16x32 MFMA.
// LDS fragment-major: MFMA-side reads are linear ds_read_b128, conflict-free.
// ---------------------------------------------------------------------------
template <int K, int N, bool EPI, bool ABF16, bool OUTB>
__global__ __launch_bounds__(256) void gemm_mfma_kernel(
    const void* __restrict__ Av, const float* __restrict__ B,
    const float* __restrict__ bias, void* __restrict__ Cv, int M) {
  __shared__ __align__(16) unsigned short Alds[4096];  // 128x32 bf16
  __shared__ __align__(16) unsigned short Blds[4096];  // 32x128 bf16
  int tid = threadIdx.x;
  int lane = tid & 63, wid = tid >> 6;
  int wm = wid >> 1, wn = wid & 1;          // 2x2 wave grid
  int rowBase = blockIdx.x * 128;
  int colBase = blockIdx.y * 128;
  // A staging coords: thread covers (m = p*32 + tid>>3, k = (tid&7)*4)
  int kg = tid & 7, mrow = tid >> 3;
  int aquad = kg >> 1, aj0 = (kg & 1) * 4;
  // B staging coords: thread covers (col = tid&127, k = p*8 + (tid>>7)*4)
  int bn = tid & 127, kh = tid >> 7;
  int NTb = bn >> 4, nloc = bn & 15;

  f32x4 acc[4][4];
#pragma unroll
  for (int mt = 0; mt < 4; ++mt)
#pragma unroll
    for (int nt = 0; nt < 4; ++nt)
      acc[mt][nt] = (f32x4){0.f, 0.f, 0.f, 0.f};

  for (int kb = 0; kb < K; kb += 32) {
    // ---- global loads ----
    float4 av[4];
    us4 av16[4];
    if constexpr (ABF16) {
      const unsigned short* A = (const unsigned short*)Av;
#pragma unroll
      for (int p = 0; p < 4; ++p) {
        int r = rowBase + p * 32 + mrow;
        av16[p] = (r < M) ? *(const us4*)(A + (size_t)r * K + kb + kg * 4)
                          : (us4){0, 0, 0, 0};
      }
    } else {
      const float* A = (const float*)Av;
#pragma unroll
      for (int p = 0; p < 4; ++p) {
        int r = rowBase + p * 32 + mrow;
        av[p] = (r < M) ? *(const float4*)(A + (size_t)r * K + kb + kg * 4)
                        : make_float4(0.f, 0.f, 0.f, 0.f);
      }
    }
    float bv[4][4];
#pragma unroll
    for (int p = 0; p < 4; ++p) {
      int k = p * 8 + kh * 4;
#pragma unroll
      for (int i = 0; i < 4; ++i)
        bv[p][i] = B[(size_t)(kb + k + i) * N + colBase + bn];
    }
    __syncthreads();  // previous iteration's LDS reads complete
    // ---- convert + LDS store (fragment-major) ----
#pragma unroll
    for (int p = 0; p < 4; ++p) {
      int m = p * 32 + mrow;
      int MT = m >> 4, mloc = m & 15;
      us4 h;
      if constexpr (ABF16) h = av16[p];
      else h = (us4){f2bf(av[p].x), f2bf(av[p].y), f2bf(av[p].z), f2bf(av[p].w)};
      *(us4*)&Alds[(((MT * 4 + aquad) * 16 + mloc) << 3) + aj0] = h;
    }
#pragma unroll
    for (int p = 0; p < 4; ++p) {
      us4 h = {f2bf(bv[p][0]), f2bf(bv[p][1]), f2bf(bv[p][2]), f2bf(bv[p][3])};
      *(us4*)&Blds[(((NTb * 4 + p) * 16 + nloc) << 3) + kh * 4] = h;
    }
    __syncthreads();
    // ---- MFMA ----
    bf16x8 af[4], bf[4];
#pragma unroll
    for (int mt = 0; mt < 4; ++mt)
      af[mt] = *(bf16x8*)&Alds[(((wm * 4 + mt) * 64 + lane)) << 3];
#pragma unroll
    for (int nt = 0; nt < 4; ++nt)
      bf[nt] = *(bf16x8*)&Blds[(((wn * 4 + nt) * 64 + lane)) << 3];
#pragma unroll
    for (int mt = 0; mt < 4; ++mt)
#pragma unroll
      for (int nt = 0; nt < 4; ++nt)
        acc[mt][nt] = __builtin_amdgcn_mfma_f32_16x16x32_bf16(
            af[mt], bf[nt], acc[mt][nt], 0, 0, 0);
  }
  // ---- epilogue: C/D layout col=lane&15, row=(lane>>4)*4+i ----
  int cquad = lane >> 4, cn = lane & 15;
#pragma unroll
  for (int nt = 0; nt < 4; ++nt) {
    int col = colBase + wn * 64 + nt * 16 + cn;
    float bb = EPI ? bias[col] : 0.f;
#pragma unroll
    for (int mt = 0; mt < 4; ++mt) {
      int r0 = rowBase + wm * 64 + mt * 16 + cquad * 4;
#pragma unroll
      for (int i = 0; i < 4; ++i) {
        int r = r0 + i;
        if (r < M) {
          float o = acc[mt][nt][i];
          if (EPI) o = fmaxf(o + bb, 0.f);
          if constexpr (OUTB)
            ((unsigned short*)Cv)[(size_t)r * N + col] = f2bf(o);
          else
            ((float*)Cv)[(size_t)r * N + col] = o;
        }
      }
    }
  }
}

// ---------------------------------------------------------------------------
extern "C" void kernel_launch(void* const* d_in, const int* in_sizes, int n_in,
                              void* d_out, int out_size, void* d_ws, size_t ws_size,
                              hipStream_t stream) {
  const float* x        = (const float*)d_in[0];
  const int*   adj_row  = (const int*)d_in[1];
  const int*   adj_col  = (const int*)d_in[2];
  const float* adj_val  = (const float*)d_in[3];
  const int*   ainv_row = (const int*)d_in[4];
  const int*   ainv_col = (const int*)d_in[5];
  const float* ainv_val = (const float*)d_in[6];
  const float* W1       = (const float*)d_in[7];
  const float* b1       = (const float*)d_in[8];
  const float* W2       = (const float*)d_in[9];
  const float* b2       = (const float*)d_in[10];

  float* out = (float*)d_out;                    // [N,512]
  float* emb = out + (size_t)NN * NFEAT;         // [N,128] (fp32 output)

  // Workspace carve (256B-aligned chunks)
  size_t off = 0;
  auto carve = [&](size_t bytes) {
    void* p = (char*)d_ws + off;
    off += (bytes + 255) & ~(size_t)255;
    return p;
  };
  unsigned short* Tb   = (unsigned short*)carve((size_t)NN * HIDD * 2);  // 12.8MB
  unsigned short* H0b  = (unsigned short*)carve((size_t)NN * HIDD * 2);  // 12.8MB
  int*  rowptr_a = (int*)carve(50004 * 4);
  int*  rowptr_b = (int*)carve(50004 * 4);
  int*  cnt_a    = (int*)carve(50004 * 4);
  int*  cnt_b    = (int*)carve(50004 * 4);
  int*  bsum_a   = (int*)carve(256 * 4);
  int*  bsum_b   = (int*)carve(256 * 4);
  int*  rank_a   = (int*)carve((size_t)NE * 4);                           // 6.4MB
  int*  rank_b   = (int*)carve((size_t)NE * 4);                           // 6.4MB
  int2* pairs_a  = (int2*)carve((size_t)NE * 8);                          // 12.8MB
  int2* pairs_b  = (int2*)carve((size_t)NE * 8);                          // 12.8MB
  // Optional bf16 copy of emb for spmm2's gather (+12.8MB) — only if ws fits.
  unsigned short* embb = (unsigned short*)((char*)d_ws + off);
  bool full = ws_size >= off + (size_t)NN * HIDD * 2;

  // ---- CSR build for both graphs (merged A/B launches) ----
  hipMemsetAsync(cnt_a, 0, NN * sizeof(int), stream);
  hipMemsetAsync(cnt_b, 0, NN * sizeof(int), stream);
  hist_rank_kernel<<<dim3(NE / 256, 2), 256, 0, stream>>>(
      adj_row, ainv_row, cnt_a, cnt_b, rank_a, rank_b, NE);
  block_sum_kernel<<<dim3(NB, 2), 256, 0, stream>>>(cnt_a, cnt_b, bsum_a, bsum_b, NN);
  scan_partials_kernel<<<2, 256, 0, stream>>>(bsum_a, bsum_b, rowptr_a, rowptr_b,
                                              NB, NN);
  scan_apply_kernel<<<dim3(NB, 2), 256, 0, stream>>>(
      cnt_a, cnt_b, bsum_a, bsum_b, rowptr_a, rowptr_b, NN);
  scatter_rank_kernel<<<dim3(NE / 256, 2), 256, 0, stream>>>(
      adj_row, adj_col, adj_val, rank_a, rowptr_a, pairs_a,
      ainv_row, ainv_col, ainv_val, rank_b, rowptr_b, pairs_b, NE);

  // ---- H0b = bf16(X @ W1) (bf16 MFMA, bf16 out) ----
  gemm_mfma_kernel<NFEAT, HIDD, false, false, true>
      <<<dim3((NN + 127) / 128, 1), 256, 0, stream>>>(x, W1, nullptr, H0b, NN);

  // ---- emb = relu(A @ H0 + b1); also bf16 copy for next gather ----
  if (full)
    spmm_kernel<true, true, true, true><<<(NN + 7) / 8, 256, 0, stream>>>(
        rowptr_a, pairs_a, H0b, b1, emb, embb, NN);
  else
    spmm_kernel<true, true, true, false><<<(NN + 7) / 8, 256, 0, stream>>>(
        rowptr_a, pairs_a, H0b, b1, emb, nullptr, NN);

  // ---- Tb = bf16(A_inv @ emb)  (reassociated: (A_inv @ h) @ W2) ----
  if (full)
    spmm_kernel<true, false, false, true><<<(NN + 7) / 8, 256, 0, stream>>>(
        rowptr_b, pairs_b, embb, nullptr, nullptr, Tb, NN);
  else
    spmm_kernel<false, false, false, true><<<(NN + 7) / 8, 256, 0, stream>>>(
        rowptr_b, pairs_b, emb, nullptr, nullptr, Tb, NN);

  // ---- out = relu(Tb @ W2 + b2) (bf16 MFMA, bf16 A operand) ----
  gemm_mfma_kernel<HIDD, NFEAT, true, true, false>
      <<<dim3((NN + 127) / 128, 4), 256, 0, stream>>>(Tb, W2, b2, out, NN);
}

// Round 6
// 634.626 us; speedup vs baseline: 1.2963x; 1.0788x over previous
//
#include <hip/hip_runtime.h>

// Problem constants (from reference)
#define NN     50000
#define NFEAT  512
#define HIDD   128
#define NE     1600000
#define NB     ((NN + 255) / 256)   // 196 blocks for per-node arrays
#define NSUB   8                    // per-row sub-counters (contention spread)

typedef __attribute__((ext_vector_type(8))) short    bf16x8;
typedef __attribute__((ext_vector_type(4))) float    f32x4;
typedef __attribute__((ext_vector_type(4))) unsigned short us4;

__device__ inline unsigned short f2bf(float f) {   // fp32 -> bf16 RNE
  unsigned int u = __float_as_uint(f);
  u += 0x7FFFu + ((u >> 16) & 1u);
  return (unsigned short)(u >> 16);
}

__device__ inline float bf2f(unsigned short h) {   // bf16 -> fp32
  return __uint_as_float((unsigned int)h << 16);
}

__device__ inline void fma4(float4& a, float v, const float4& d) {
  a.x = fmaf(v, d.x, a.x);
  a.y = fmaf(v, d.y, a.y);
  a.z = fmaf(v, d.z, a.z);
  a.w = fmaf(v, d.w, a.w);
}

__device__ inline void fma4b(float4& a, float v, us4 d) {
  a.x = fmaf(v, bf2f(d[0]), a.x);
  a.y = fmaf(v, bf2f(d[1]), a.y);
  a.z = fmaf(v, bf2f(d[2]), a.z);
  a.w = fmaf(v, bf2f(d[3]), a.w);
}

// ---------------------------------------------------------------------------
// Hist + rank with NSUB-way sub-counters: rnk[i] = old value of
// cnt8[(i&7)][row[i]]. Mechanism probe for the ~20 G atomics/s wall observed
// in round 5: same op count, ~8x less per-address contention. If dur is
// unchanged -> global fabric atomic-rate wall (next: LDS counting sort);
// if it collapses -> per-address serialization was the limit.
// ---------------------------------------------------------------------------
__global__ __launch_bounds__(256) void hist_rank_kernel(
    const int* __restrict__ rowA, const int* __restrict__ rowB,
    int* __restrict__ cnt8A, int* __restrict__ cnt8B,
    int* __restrict__ rnkA, int* __restrict__ rnkB, int e) {
  const int* row  = blockIdx.y ? rowB : rowA;
  int*       cnt8 = blockIdx.y ? cnt8B : cnt8A;
  int*       rnk  = blockIdx.y ? rnkB : rnkA;
  int i = blockIdx.x * 256 + threadIdx.x;
  if (i < e) {
    int sub = i & (NSUB - 1);
    rnk[i] = atomicAdd(&cnt8[sub * NN + row[i]], 1);
  }
}

// ---------------------------------------------------------------------------
// Scan phase 1: per-block sums of total counts (sum of 8 sub-counters).
// ---------------------------------------------------------------------------
__global__ __launch_bounds__(256) void block_sum_kernel(
    const int* __restrict__ cnt8A, const int* __restrict__ cnt8B,
    int* __restrict__ bsumA, int* __restrict__ bsumB, int n) {
  const int* cnt8 = blockIdx.y ? cnt8B : cnt8A;
  int*       bsum = blockIdx.y ? bsumB : bsumA;
  __shared__ int ws[4];
  int i = blockIdx.x * 256 + threadIdx.x;
  int lane = threadIdx.x & 63, wid = threadIdx.x >> 6;
  int v = 0;
  if (i < n) {
#pragma unroll
    for (int s = 0; s < NSUB; ++s) v += cnt8[s * NN + i];
  }
#pragma unroll
  for (int off = 32; off > 0; off >>= 1) v += __shfl_down(v, off, 64);
  if (lane == 0) ws[wid] = v;
  __syncthreads();
  if (threadIdx.x == 0) bsum[blockIdx.x] = ws[0] + ws[1] + ws[2] + ws[3];
}

// ---------------------------------------------------------------------------
// Scan phase 2: one block per graph, exclusive-scan nb partials in place;
// write grand total to rowptr[NN].
// ---------------------------------------------------------------------------
__global__ __launch_bounds__(256) void scan_partials_kernel(
    int* __restrict__ bsumA, int* __restrict__ bsumB,
    int* __restrict__ rpA, int* __restrict__ rpB, int nb, int nfull) {
  int* bsum   = blockIdx.x ? bsumB : bsumA;
  int* rowptr = blockIdx.x ? rpB : rpA;
  __shared__ int ws[4];
  int t = threadIdx.x;
  int lane = t & 63, wid = t >> 6;
  int v = (t < nb) ? bsum[t] : 0;
  int incl = v;
#pragma unroll
  for (int off = 1; off < 64; off <<= 1) {
    int u = __shfl_up(incl, off, 64);
    if (lane >= off) incl += u;
  }
  if (lane == 63) ws[wid] = incl;
  __syncthreads();
  int wprefix = 0;
  for (int w = 0; w < wid; ++w) wprefix += ws[w];
  incl += wprefix;
  if (t < nb) bsum[t] = incl - v;          // exclusive
  if (t == nb - 1) rowptr[nfull] = incl;   // grand total
}

// ---------------------------------------------------------------------------
// Scan phase 3: rowptr[i] = exclusive scan of per-row totals; also emit
// per-(sub,row) scatter bases: sb8[s][i] = rowptr[i] + sum_{s'<s} cnt8[s'][i]
// so the scatter is a pure indexed store (zero atomics).
// ---------------------------------------------------------------------------
__global__ __launch_bounds__(256) void scan_apply_kernel(
    const int* __restrict__ cnt8A, const int* __restrict__ cnt8B,
    const int* __restrict__ bsumA, const int* __restrict__ bsumB,
    int* __restrict__ rpA, int* __restrict__ rpB,
    int* __restrict__ sb8A, int* __restrict__ sb8B, int n) {
  const int* cnt8 = blockIdx.y ? cnt8B : cnt8A;
  const int* bsum = blockIdx.y ? bsumB : bsumA;
  int*       rowptr = blockIdx.y ? rpB : rpA;
  int*       sb8  = blockIdx.y ? sb8B : sb8A;
  __shared__ int ws[4];
  int i = blockIdx.x * 256 + threadIdx.x;
  int lane = threadIdx.x & 63, wid = threadIdx.x >> 6;
  int sc[NSUB];
  int v = 0;
  if (i < n) {
#pragma unroll
    for (int s = 0; s < NSUB; ++s) { sc[s] = cnt8[s * NN + i]; v += sc[s]; }
  }
  int incl = v;
#pragma unroll
  for (int off = 1; off < 64; off <<= 1) {
    int u = __shfl_up(incl, off, 64);
    if (lane >= off) incl += u;
  }
  if (lane == 63) ws[wid] = incl;
  __syncthreads();
  int wprefix = 0;
  for (int w = 0; w < wid; ++w) wprefix += ws[w];
  if (i < n) {
    int base = bsum[blockIdx.x] + wprefix + (incl - v);
    rowptr[i] = base;
#pragma unroll
    for (int s = 0; s < NSUB; ++s) { sb8[s * NN + i] = base; base += sc[s]; }
  }
}

// ---------------------------------------------------------------------------
// Rank-based scatter, ZERO atomics: p = sb8[i&7][row[i]] + rnk[i] is unique
// by construction (ranks partition each (sub,row) segment). Plain int2
// stores: L2 write-back is byte-masked, so cross-XCD neighbors in a 64B
// line merge correctly (rounds 0-3 relied on the same property).
// ---------------------------------------------------------------------------
__global__ __launch_bounds__(256) void scatter_rank_kernel(
    const int* __restrict__ rowA, const int* __restrict__ colA,
    const float* __restrict__ valA, const int* __restrict__ rnkA,
    const int* __restrict__ sb8A, int2* __restrict__ pairsA,
    const int* __restrict__ rowB, const int* __restrict__ colB,
    const float* __restrict__ valB, const int* __restrict__ rnkB,
    const int* __restrict__ sb8B, int2* __restrict__ pairsB, int e) {
  const int*   row   = blockIdx.y ? rowB : rowA;
  const int*   col   = blockIdx.y ? colB : colA;
  const float* val   = blockIdx.y ? valB : valA;
  const int*   rnk   = blockIdx.y ? rnkB : rnkA;
  const int*   sb8   = blockIdx.y ? sb8B : sb8A;
  int2*        pairs = blockIdx.y ? pairsB : pairsA;
  int i = blockIdx.x * 256 + threadIdx.x;
  if (i < e) {
    int sub = i & (NSUB - 1);
    int p = sb8[sub * NN + row[i]] + rnk[i];
    pairs[p] = make_int2(col[i], __float_as_int(val[i]));
  }
}

// ---------------------------------------------------------------------------
// CSR SpMM, D=128. One 32-lane group per row, 8-wide edge unroll.
// bf16 dense (DB16) halves gather bytes AND footprint (25.6->12.8 MB).
// Outputs: optional fp32 (WF32) and/or bf16 copy (WB16) for next consumer.
// ---------------------------------------------------------------------------
template <bool DB16, bool EPI, bool WF32, bool WB16>
__global__ __launch_bounds__(256) void spmm_kernel(
    const int* __restrict__ rowptr, const int2* __restrict__ pairs,
    const void* __restrict__ dense, const float* __restrict__ bias,
    float* __restrict__ outf, unsigned short* __restrict__ outb, int n) {
  int r = blockIdx.x * 8 + (threadIdx.x >> 5);
  if (r >= n) return;
  int c4 = (threadIdx.x & 31);  // 4-feature chunk index within row
  int s = rowptr[r], e = rowptr[r + 1];
  float4 a0 = make_float4(0.f, 0.f, 0.f, 0.f);
  float4 a1 = a0, a2 = a0, a3 = a0;
  int j = s;
  if constexpr (DB16) {
    const unsigned short* d16 = (const unsigned short*)dense;
    for (; j + 8 <= e; j += 8) {
      int2 p0 = pairs[j + 0], p1 = pairs[j + 1], p2 = pairs[j + 2], p3 = pairs[j + 3];
      int2 p4 = pairs[j + 4], p5 = pairs[j + 5], p6 = pairs[j + 6], p7 = pairs[j + 7];
      us4 d0 = *(const us4*)(d16 + (size_t)p0.x * 128 + c4 * 4);
      us4 d1 = *(const us4*)(d16 + (size_t)p1.x * 128 + c4 * 4);
      us4 d2 = *(const us4*)(d16 + (size_t)p2.x * 128 + c4 * 4);
      us4 d3 = *(const us4*)(d16 + (size_t)p3.x * 128 + c4 * 4);
      us4 d4 = *(const us4*)(d16 + (size_t)p4.x * 128 + c4 * 4);
      us4 d5 = *(const us4*)(d16 + (size_t)p5.x * 128 + c4 * 4);
      us4 d6 = *(const us4*)(d16 + (size_t)p6.x * 128 + c4 * 4);
      us4 d7 = *(const us4*)(d16 + (size_t)p7.x * 128 + c4 * 4);
      fma4b(a0, __int_as_float(p0.y), d0);
      fma4b(a1, __int_as_float(p1.y), d1);
      fma4b(a2, __int_as_float(p2.y), d2);
      fma4b(a3, __int_as_float(p3.y), d3);
      fma4b(a0, __int_as_float(p4.y), d4);
      fma4b(a1, __int_as_float(p5.y), d5);
      fma4b(a2, __int_as_float(p6.y), d6);
      fma4b(a3, __int_as_float(p7.y), d7);
    }
    for (; j < e; ++j) {
      int2 ev = pairs[j];
      us4 d = *(const us4*)(d16 + (size_t)ev.x * 128 + c4 * 4);
      fma4b(a0, __int_as_float(ev.y), d);
    }
  } else {
    const float4* dense4 = (const float4*)dense;
    for (; j + 8 <= e; j += 8) {
      int2 p0 = pairs[j + 0], p1 = pairs[j + 1], p2 = pairs[j + 2], p3 = pairs[j + 3];
      int2 p4 = pairs[j + 4], p5 = pairs[j + 5], p6 = pairs[j + 6], p7 = pairs[j + 7];
      float4 d0 = dense4[(size_t)p0.x * 32 + c4];
      float4 d1 = dense4[(size_t)p1.x * 32 + c4];
      float4 d2 = dense4[(size_t)p2.x * 32 + c4];
      float4 d3 = dense4[(size_t)p3.x * 32 + c4];
      float4 d4 = dense4[(size_t)p4.x * 32 + c4];
      float4 d5 = dense4[(size_t)p5.x * 32 + c4];
      float4 d6 = dense4[(size_t)p6.x * 32 + c4];
      float4 d7 = dense4[(size_t)p7.x * 32 + c4];
      fma4(a0, __int_as_float(p0.y), d0);
      fma4(a1, __int_as_float(p1.y), d1);
      fma4(a2, __int_as_float(p2.y), d2);
      fma4(a3, __int_as_float(p3.y), d3);
      fma4(a0, __int_as_float(p4.y), d4);
      fma4(a1, __int_as_float(p5.y), d5);
      fma4(a2, __int_as_float(p6.y), d6);
      fma4(a3, __int_as_float(p7.y), d7);
    }
    for (; j < e; ++j) {
      int2 ev = pairs[j];
      float4 d = dense4[(size_t)ev.x * 32 + c4];
      fma4(a0, __int_as_float(ev.y), d);
    }
  }
  float4 acc;
  acc.x = (a0.x + a1.x) + (a2.x + a3.x);
  acc.y = (a0.y + a1.y) + (a2.y + a3.y);
  acc.z = (a0.z + a1.z) + (a2.z + a3.z);
  acc.w = (a0.w + a1.w) + (a2.w + a3.w);
  if (EPI) {
    float4 b = ((const float4*)bias)[c4];
    acc.x = fmaxf(acc.x + b.x, 0.f);
    acc.y = fmaxf(acc.y + b.y, 0.f);
    acc.z = fmaxf(acc.z + b.z, 0.f);
    acc.w = fmaxf(acc.w + b.w, 0.f);
  }
  if (WF32)
    *(float4*)(outf + (size_t)r * 128 + c4 * 4) = acc;
  if (WB16) {
    us4 h = {f2bf(acc.x), f2bf(acc.y), f2bf(acc.z), f2bf(acc.w)};
    *(us4*)(outb + (size_t)r * 128 + c4 * 4) = h;
  }
}

// ---------------------------------------------------------------------------
// bf16-MFMA GEMM: C[M,N] = A[M,K]@B[K,N] (+bias,relu if EPI). B fp32.
// A fp32 (converted during staging) or bf16 (ABF16 - staged directly).
// C fp32 or bf16 (OUTB). 128x128 tile, BK=32, 4 waves, 16x16x32 MFMA.
// LDS fragment-major: MFMA-side reads are linear ds_read_b128, conflict-free.
// ---------------------------------------------------------------------------
template <int K, int N, bool EPI, bool ABF16, bool OUTB>
__global__ __launch_bounds__(256) void gemm_mfma_kernel(
    const void* __restrict__ Av, const float* __restrict__ B,
    const float* __restrict__ bias, void* __restrict__ Cv, int M) {
  __shared__ __align__(16) unsigned short Alds[4096];  // 128x32 bf16
  __shared__ __align__(16) unsigned short Blds[4096];  // 32x128 bf16
  int tid = threadIdx.x;
  int lane = tid & 63, wid = tid >> 6;
  int wm = wid >> 1, wn = wid & 1;          // 2x2 wave grid
  int rowBase = blockIdx.x * 128;
  int colBase = blockIdx.y * 128;
  // A staging coords: thread covers (m = p*32 + tid>>3, k = (tid&7)*4)
  int kg = tid & 7, mrow = tid >> 3;
  int aquad = kg >> 1, aj0 = (kg & 1) * 4;
  // B staging coords: thread covers (col = tid&127, k = p*8 + (tid>>7)*4)
  int bn = tid & 127, kh = tid >> 7;
  int NTb = bn >> 4, nloc = bn & 15;

  f32x4 acc[4][4];
#pragma unroll
  for (int mt = 0; mt < 4; ++mt)
#pragma unroll
    for (int nt = 0; nt < 4; ++nt)
      acc[mt][nt] = (f32x4){0.f, 0.f, 0.f, 0.f};

  for (int kb = 0; kb < K; kb += 32) {
    // ---- global loads ----
    float4 av[4];
    us4 av16[4];
    if constexpr (ABF16) {
      const unsigned short* A = (const unsigned short*)Av;
#pragma unroll
      for (int p = 0; p < 4; ++p) {
        int r = rowBase + p * 32 + mrow;
        av16[p] = (r < M) ? *(const us4*)(A + (size_t)r * K + kb + kg * 4)
                          : (us4){0, 0, 0, 0};
      }
    } else {
      const float* A = (const float*)Av;
#pragma unroll
      for (int p = 0; p < 4; ++p) {
        int r = rowBase + p * 32 + mrow;
        av[p] = (r < M) ? *(const float4*)(A + (size_t)r * K + kb + kg * 4)
                        : make_float4(0.f, 0.f, 0.f, 0.f);
      }
    }
    float bv[4][4];
#pragma unroll
    for (int p = 0; p < 4; ++p) {
      int k = p * 8 + kh * 4;
#pragma unroll
      for (int i = 0; i < 4; ++i)
        bv[p][i] = B[(size_t)(kb + k + i) * N + colBase + bn];
    }
    __syncthreads();  // previous iteration's LDS reads complete
    // ---- convert + LDS store (fragment-major) ----
#pragma unroll
    for (int p = 0; p < 4; ++p) {
      int m = p * 32 + mrow;
      int MT = m >> 4, mloc = m & 15;
      us4 h;
      if constexpr (ABF16) h = av16[p];
      else h = (us4){f2bf(av[p].x), f2bf(av[p].y), f2bf(av[p].z), f2bf(av[p].w)};
      *(us4*)&Alds[(((MT * 4 + aquad) * 16 + mloc) << 3) + aj0] = h;
    }
#pragma unroll
    for (int p = 0; p < 4; ++p) {
      us4 h = {f2bf(bv[p][0]), f2bf(bv[p][1]), f2bf(bv[p][2]), f2bf(bv[p][3])};
      *(us4*)&Blds[(((NTb * 4 + p) * 16 + nloc) << 3) + kh * 4] = h;
    }
    __syncthreads();
    // ---- MFMA ----
    bf16x8 af[4], bf[4];
#pragma unroll
    for (int mt = 0; mt < 4; ++mt)
      af[mt] = *(bf16x8*)&Alds[(((wm * 4 + mt) * 64 + lane)) << 3];
#pragma unroll
    for (int nt = 0; nt < 4; ++nt)
      bf[nt] = *(bf16x8*)&Blds[(((wn * 4 + nt) * 64 + lane)) << 3];
#pragma unroll
    for (int mt = 0; mt < 4; ++mt)
#pragma unroll
      for (int nt = 0; nt < 4; ++nt)
        acc[mt][nt] = __builtin_amdgcn_mfma_f32_16x16x32_bf16(
            af[mt], bf[nt], acc[mt][nt], 0, 0, 0);
  }
  // ---- epilogue: C/D layout col=lane&15, row=(lane>>4)*4+i ----
  int cquad = lane >> 4, cn = lane & 15;
#pragma unroll
  for (int nt = 0; nt < 4; ++nt) {
    int col = colBase + wn * 64 + nt * 16 + cn;
    float bb = EPI ? bias[col] : 0.f;
#pragma unroll
    for (int mt = 0; mt < 4; ++mt) {
      int r0 = rowBase + wm * 64 + mt * 16 + cquad * 4;
#pragma unroll
      for (int i = 0; i < 4; ++i) {
        int r = r0 + i;
        if (r < M) {
          float o = acc[mt][nt][i];
          if (EPI) o = fmaxf(o + bb, 0.f);
          if constexpr (OUTB)
            ((unsigned short*)Cv)[(size_t)r * N + col] = f2bf(o);
          else
            ((float*)Cv)[(size_t)r * N + col] = o;
        }
      }
    }
  }
}

// ---------------------------------------------------------------------------
extern "C" void kernel_launch(void* const* d_in, const int* in_sizes, int n_in,
                              void* d_out, int out_size, void* d_ws, size_t ws_size,
                              hipStream_t stream) {
  const float* x        = (const float*)d_in[0];
  const int*   adj_row  = (const int*)d_in[1];
  const int*   adj_col  = (const int*)d_in[2];
  const float* adj_val  = (const float*)d_in[3];
  const int*   ainv_row = (const int*)d_in[4];
  const int*   ainv_col = (const int*)d_in[5];
  const float* ainv_val = (const float*)d_in[6];
  const float* W1       = (const float*)d_in[7];
  const float* b1       = (const float*)d_in[8];
  const float* W2       = (const float*)d_in[9];
  const float* b2       = (const float*)d_in[10];

  float* out = (float*)d_out;                    // [N,512]
  float* emb = out + (size_t)NN * NFEAT;         // [N,128] (fp32 output)

  // Workspace carve (256B-aligned chunks)
  size_t off = 0;
  auto carve = [&](size_t bytes) {
    void* p = (char*)d_ws + off;
    off += (bytes + 255) & ~(size_t)255;
    return p;
  };
  unsigned short* Tb   = (unsigned short*)carve((size_t)NN * HIDD * 2);  // 12.8MB
  unsigned short* H0b  = (unsigned short*)carve((size_t)NN * HIDD * 2);  // 12.8MB
  int*  rowptr_a = (int*)carve(50004 * 4);
  int*  rowptr_b = (int*)carve(50004 * 4);
  int*  cnt8_a   = (int*)carve((size_t)NSUB * NN * 4);                    // 1.6MB
  int*  cnt8_b   = (int*)carve((size_t)NSUB * NN * 4);                    // 1.6MB
  int*  sb8_a    = (int*)carve((size_t)NSUB * NN * 4);                    // 1.6MB
  int*  sb8_b    = (int*)carve((size_t)NSUB * NN * 4);                    // 1.6MB
  int*  bsum_a   = (int*)carve(256 * 4);
  int*  bsum_b   = (int*)carve(256 * 4);
  int*  rank_a   = (int*)carve((size_t)NE * 4);                           // 6.4MB
  int*  rank_b   = (int*)carve((size_t)NE * 4);                           // 6.4MB
  int2* pairs_a  = (int2*)carve((size_t)NE * 8);                          // 12.8MB
  int2* pairs_b  = (int2*)carve((size_t)NE * 8);                          // 12.8MB
  // Optional bf16 copy of emb for spmm2's gather (+12.8MB) — only if ws fits.
  unsigned short* embb = (unsigned short*)((char*)d_ws + off);
  bool full = ws_size >= off + (size_t)NN * HIDD * 2;

  // ---- CSR build for both graphs (merged A/B launches) ----
  hipMemsetAsync(cnt8_a, 0, (size_t)NSUB * NN * sizeof(int), stream);
  hipMemsetAsync(cnt8_b, 0, (size_t)NSUB * NN * sizeof(int), stream);
  hist_rank_kernel<<<dim3(NE / 256, 2), 256, 0, stream>>>(
      adj_row, ainv_row, cnt8_a, cnt8_b, rank_a, rank_b, NE);
  block_sum_kernel<<<dim3(NB, 2), 256, 0, stream>>>(cnt8_a, cnt8_b, bsum_a, bsum_b, NN);
  scan_partials_kernel<<<2, 256, 0, stream>>>(bsum_a, bsum_b, rowptr_a, rowptr_b,
                                              NB, NN);
  scan_apply_kernel<<<dim3(NB, 2), 256, 0, stream>>>(
      cnt8_a, cnt8_b, bsum_a, bsum_b, rowptr_a, rowptr_b, sb8_a, sb8_b, NN);
  scatter_rank_kernel<<<dim3(NE / 256, 2), 256, 0, stream>>>(
      adj_row, adj_col, adj_val, rank_a, sb8_a, pairs_a,
      ainv_row, ainv_col, ainv_val, rank_b, sb8_b, pairs_b, NE);

  // ---- H0b = bf16(X @ W1) (bf16 MFMA, bf16 out) ----
  gemm_mfma_kernel<NFEAT, HIDD, false, false, true>
      <<<dim3((NN + 127) / 128, 1), 256, 0, stream>>>(x, W1, nullptr, H0b, NN);

  // ---- emb = relu(A @ H0 + b1); also bf16 copy for next gather ----
  if (full)
    spmm_kernel<true, true, true, true><<<(NN + 7) / 8, 256, 0, stream>>>(
        rowptr_a, pairs_a, H0b, b1, emb, embb, NN);
  else
    spmm_kernel<true, true, true, false><<<(NN + 7) / 8, 256, 0, stream>>>(
        rowptr_a, pairs_a, H0b, b1, emb, nullptr, NN);

  // ---- Tb = bf16(A_inv @ emb)  (reassociated: (A_inv @ h) @ W2) ----
  if (full)
    spmm_kernel<true, false, false, true><<<(NN + 7) / 8, 256, 0, stream>>>(
        rowptr_b, pairs_b, embb, nullptr, nullptr, Tb, NN);
  else
    spmm_kernel<false, false, false, true><<<(NN + 7) / 8, 256, 0, stream>>>(
        rowptr_b, pairs_b, emb, nullptr, nullptr, Tb, NN);

  // ---- out = relu(Tb @ W2 + b2) (bf16 MFMA, bf16 A operand) ----
  gemm_mfma_kernel<HIDD, NFEAT, true, true, false>
      <<<dim3((NN + 127) / 128, 4), 256, 0, stream>>>(Tb, W2, b2, out, NN);
}

// Round 7
// 628.018 us; speedup vs baseline: 1.3099x; 1.0105x over previous
//
#include <hip/hip_runtime.h>

// Problem constants (from reference)
#define NN     50000
#define NFEAT  512
#define HIDD   128
#define NE     1600000
#define NB     ((NN + 255) / 256)   // 196 blocks for per-node arrays
#define NCH    64                   // chunks per graph (1 block each)
#define CHSZ   (NE / NCH)           // 25000 edges per chunk (exact)
#define NWRD   (NN / 2)             // 25000 packed 2x16-bit count words

typedef __attribute__((ext_vector_type(8))) short    bf16x8;
typedef __attribute__((ext_vector_type(4))) float    f32x4;
typedef __attribute__((ext_vector_type(4))) unsigned short us4;

__device__ inline unsigned short f2bf(float f) {   // fp32 -> bf16 RNE
  unsigned int u = __float_as_uint(f);
  u += 0x7FFFu + ((u >> 16) & 1u);
  return (unsigned short)(u >> 16);
}

__device__ inline float bf2f(unsigned short h) {   // bf16 -> fp32
  return __uint_as_float((unsigned int)h << 16);
}

__device__ inline void fma4(float4& a, float v, const float4& d) {
  a.x = fmaf(v, d.x, a.x);
  a.y = fmaf(v, d.y, a.y);
  a.z = fmaf(v, d.z, a.z);
  a.w = fmaf(v, d.w, a.w);
}

__device__ inline void fma4b(float4& a, float v, us4 d) {
  a.x = fmaf(v, bf2f(d[0]), a.x);
  a.y = fmaf(v, bf2f(d[1]), a.y);
  a.z = fmaf(v, bf2f(d[2]), a.z);
  a.w = fmaf(v, bf2f(d[3]), a.w);
}

// ---------------------------------------------------------------------------
// Chunked LDS histogram: round-6 showed global atomics wall at ~24 G ops/s
// (NSUB spread 155->135us only). Replace 3.2M fabric atomics with LDS
// atomics: full row space fits one workgroup's LDS as 2x16-bit packed
// counts (50000 rows -> 25000 words = 100KB <= 160KB). One block per
// 25000-edge chunk; writes its final count vector to cnt16[chunk].
// ---------------------------------------------------------------------------
__global__ __launch_bounds__(256) void chunk_hist_kernel(
    const int* __restrict__ rowA, const int* __restrict__ rowB,
    unsigned int* __restrict__ cntA, unsigned int* __restrict__ cntB) {
  __shared__ unsigned int lcnt[NWRD];
  const int*    row = blockIdx.y ? rowB : rowA;
  unsigned int* cnt = blockIdx.y ? cntB : cntA;
  int b = blockIdx.x;
  for (int w = threadIdx.x; w < NWRD; w += 256) lcnt[w] = 0;
  __syncthreads();
  int base = b * CHSZ;
  for (int j = threadIdx.x; j < CHSZ; j += 256) {
    int r = row[base + j];
    atomicAdd(&lcnt[r >> 1], 1u << ((r & 1) * 16));
  }
  __syncthreads();
  unsigned int* dst = cnt + (size_t)b * NWRD;
  for (int w = threadIdx.x; w < NWRD; w += 256) dst[w] = lcnt[w];
}

// ---------------------------------------------------------------------------
// Scan phase 1: per-block (256-row) sums of per-row totals across chunks.
// ---------------------------------------------------------------------------
__global__ __launch_bounds__(256) void block_sum_kernel(
    const unsigned int* __restrict__ cntA, const unsigned int* __restrict__ cntB,
    int* __restrict__ bsumA, int* __restrict__ bsumB, int n) {
  const unsigned int* cnt = blockIdx.y ? cntB : cntA;
  int*                bsum = blockIdx.y ? bsumB : bsumA;
  __shared__ int ws[4];
  int i = blockIdx.x * 256 + threadIdx.x;
  int lane = threadIdx.x & 63, wid = threadIdx.x >> 6;
  int v = 0;
  if (i < n) {
    const unsigned int* cw = cnt + (i >> 1);
    int sh = (i & 1) * 16;
    for (int b = 0; b < NCH; ++b)
      v += (int)((cw[(size_t)b * NWRD] >> sh) & 0xFFFFu);
  }
#pragma unroll
  for (int off = 32; off > 0; off >>= 1) v += __shfl_down(v, off, 64);
  if (lane == 0) ws[wid] = v;
  __syncthreads();
  if (threadIdx.x == 0) bsum[blockIdx.x] = ws[0] + ws[1] + ws[2] + ws[3];
}

// ---------------------------------------------------------------------------
// Scan phase 2: one block per graph, exclusive-scan nb partials in place;
// write grand total to rowptr[NN].
// ---------------------------------------------------------------------------
__global__ __launch_bounds__(256) void scan_partials_kernel(
    int* __restrict__ bsumA, int* __restrict__ bsumB,
    int* __restrict__ rpA, int* __restrict__ rpB, int nb, int nfull) {
  int* bsum   = blockIdx.x ? bsumB : bsumA;
  int* rowptr = blockIdx.x ? rpB : rpA;
  __shared__ int ws[4];
  int t = threadIdx.x;
  int lane = t & 63, wid = t >> 6;
  int v = (t < nb) ? bsum[t] : 0;
  int incl = v;
#pragma unroll
  for (int off = 1; off < 64; off <<= 1) {
    int u = __shfl_up(incl, off, 64);
    if (lane >= off) incl += u;
  }
  if (lane == 63) ws[wid] = incl;
  __syncthreads();
  int wprefix = 0;
  for (int w = 0; w < wid; ++w) wprefix += ws[w];
  incl += wprefix;
  if (t < nb) bsum[t] = incl - v;          // exclusive
  if (t == nb - 1) rowptr[nfull] = incl;   // grand total
}

// ---------------------------------------------------------------------------
// Scan phase 3: rowptr[i] = exclusive scan of per-row totals; also emit
// per-chunk scatter bases base32[b][i] = rowptr[i] + sum_{b'<b} cnt[b'][i]
// so the scatter is a pure indexed store (zero atomics). Writes for fixed b
// are coalesced across threads.
// ---------------------------------------------------------------------------
__global__ __launch_bounds__(256) void scan_apply_kernel(
    const unsigned int* __restrict__ cntA, const unsigned int* __restrict__ cntB,
    const int* __restrict__ bsumA, const int* __restrict__ bsumB,
    int* __restrict__ rpA, int* __restrict__ rpB,
    int* __restrict__ baseA, int* __restrict__ baseB, int n) {
  const unsigned int* cnt = blockIdx.y ? cntB : cntA;
  const int* bsum = blockIdx.y ? bsumB : bsumA;
  int*       rowptr = blockIdx.y ? rpB : rpA;
  int*       base32 = blockIdx.y ? baseB : baseA;
  __shared__ int ws[4];
  int i = blockIdx.x * 256 + threadIdx.x;
  int lane = threadIdx.x & 63, wid = threadIdx.x >> 6;
  int v = 0, sh = 0;
  const unsigned int* cw = nullptr;
  if (i < n) {
    cw = cnt + (i >> 1);
    sh = (i & 1) * 16;
    for (int b = 0; b < NCH; ++b)
      v += (int)((cw[(size_t)b * NWRD] >> sh) & 0xFFFFu);
  }
  int incl = v;
#pragma unroll
  for (int off = 1; off < 64; off <<= 1) {
    int u = __shfl_up(incl, off, 64);
    if (lane >= off) incl += u;
  }
  if (lane == 63) ws[wid] = incl;
  __syncthreads();
  int wprefix = 0;
  for (int w = 0; w < wid; ++w) wprefix += ws[w];
  if (i < n) {
    int run = bsum[blockIdx.x] + wprefix + (incl - v);
    rowptr[i] = run;
    for (int b = 0; b < NCH; ++b) {
      base32[(size_t)b * NN + i] = run;
      run += (int)((cw[(size_t)b * NWRD] >> sh) & 0xFFFFu);
    }
  }
}

// ---------------------------------------------------------------------------
// Chunked scatter, ZERO global atomics: re-derives a local rank with a
// second LDS-atomic pass (any permutation of a (chunk,row) segment is a
// valid rank assignment; within-row order is free under segment-sum), then
// p = base32[chunk][row] + local_rank is globally unique. base32 slice per
// chunk is 200KB -> L2-resident for the owning block's gathers.
// ---------------------------------------------------------------------------
__global__ __launch_bounds__(256) void scatter_chunk_kernel(
    const int* __restrict__ rowA, const int* __restrict__ colA,
    const float* __restrict__ valA, const int* __restrict__ baseA,
    int2* __restrict__ pairsA,
    const int* __restrict__ rowB, const int* __restrict__ colB,
    const float* __restrict__ valB, const int* __restrict__ baseB,
    int2* __restrict__ pairsB) {
  __shared__ unsigned int lcnt[NWRD];
  const int*   row    = blockIdx.y ? rowB : rowA;
  const int*   col    = blockIdx.y ? colB : colA;
  const float* val    = blockIdx.y ? valB : valA;
  const int*   base32 = blockIdx.y ? baseB : baseA;
  int2*        pairs  = blockIdx.y ? pairsB : pairsA;
  int b = blockIdx.x;
  for (int w = threadIdx.x; w < NWRD; w += 256) lcnt[w] = 0;
  __syncthreads();
  int base = b * CHSZ;
  const int* bslice = base32 + (size_t)b * NN;
  for (int j = threadIdx.x; j < CHSZ; j += 256) {
    int i = base + j;
    int r = row[i];
    int sh = (r & 1) * 16;
    int lr = (int)((atomicAdd(&lcnt[r >> 1], 1u << sh) >> sh) & 0xFFFFu);
    int p = bslice[r] + lr;
    pairs[p] = make_int2(col[i], __float_as_int(val[i]));
  }
}

// ---------------------------------------------------------------------------
// CSR SpMM, D=128. One 32-lane group per row, 8-wide edge unroll.
// bf16 dense (DB16) halves gather bytes AND footprint (25.6->12.8 MB).
// Outputs: optional fp32 (WF32) and/or bf16 copy (WB16) for next consumer.
// ---------------------------------------------------------------------------
template <bool DB16, bool EPI, bool WF32, bool WB16>
__global__ __launch_bounds__(256) void spmm_kernel(
    const int* __restrict__ rowptr, const int2* __restrict__ pairs,
    const void* __restrict__ dense, const float* __restrict__ bias,
    float* __restrict__ outf, unsigned short* __restrict__ outb, int n) {
  int r = blockIdx.x * 8 + (threadIdx.x >> 5);
  if (r >= n) return;
  int c4 = (threadIdx.x & 31);  // 4-feature chunk index within row
  int s = rowptr[r], e = rowptr[r + 1];
  float4 a0 = make_float4(0.f, 0.f, 0.f, 0.f);
  float4 a1 = a0, a2 = a0, a3 = a0;
  int j = s;
  if constexpr (DB16) {
    const unsigned short* d16 = (const unsigned short*)dense;
    for (; j + 8 <= e; j += 8) {
      int2 p0 = pairs[j + 0], p1 = pairs[j + 1], p2 = pairs[j + 2], p3 = pairs[j + 3];
      int2 p4 = pairs[j + 4], p5 = pairs[j + 5], p6 = pairs[j + 6], p7 = pairs[j + 7];
      us4 d0 = *(const us4*)(d16 + (size_t)p0.x * 128 + c4 * 4);
      us4 d1 = *(const us4*)(d16 + (size_t)p1.x * 128 + c4 * 4);
      us4 d2 = *(const us4*)(d16 + (size_t)p2.x * 128 + c4 * 4);
      us4 d3 = *(const us4*)(d16 + (size_t)p3.x * 128 + c4 * 4);
      us4 d4 = *(const us4*)(d16 + (size_t)p4.x * 128 + c4 * 4);
      us4 d5 = *(const us4*)(d16 + (size_t)p5.x * 128 + c4 * 4);
      us4 d6 = *(const us4*)(d16 + (size_t)p6.x * 128 + c4 * 4);
      us4 d7 = *(const us4*)(d16 + (size_t)p7.x * 128 + c4 * 4);
      fma4b(a0, __int_as_float(p0.y), d0);
      fma4b(a1, __int_as_float(p1.y), d1);
      fma4b(a2, __int_as_float(p2.y), d2);
      fma4b(a3, __int_as_float(p3.y), d3);
      fma4b(a0, __int_as_float(p4.y), d4);
      fma4b(a1, __int_as_float(p5.y), d5);
      fma4b(a2, __int_as_float(p6.y), d6);
      fma4b(a3, __int_as_float(p7.y), d7);
    }
    for (; j < e; ++j) {
      int2 ev = pairs[j];
      us4 d = *(const us4*)(d16 + (size_t)ev.x * 128 + c4 * 4);
      fma4b(a0, __int_as_float(ev.y), d);
    }
  } else {
    const float4* dense4 = (const float4*)dense;
    for (; j + 8 <= e; j += 8) {
      int2 p0 = pairs[j + 0], p1 = pairs[j + 1], p2 = pairs[j + 2], p3 = pairs[j + 3];
      int2 p4 = pairs[j + 4], p5 = pairs[j + 5], p6 = pairs[j + 6], p7 = pairs[j + 7];
      float4 d0 = dense4[(size_t)p0.x * 32 + c4];
      float4 d1 = dense4[(size_t)p1.x * 32 + c4];
      float4 d2 = dense4[(size_t)p2.x * 32 + c4];
      float4 d3 = dense4[(size_t)p3.x * 32 + c4];
      float4 d4 = dense4[(size_t)p4.x * 32 + c4];
      float4 d5 = dense4[(size_t)p5.x * 32 + c4];
      float4 d6 = dense4[(size_t)p6.x * 32 + c4];
      float4 d7 = dense4[(size_t)p7.x * 32 + c4];
      fma4(a0, __int_as_float(p0.y), d0);
      fma4(a1, __int_as_float(p1.y), d1);
      fma4(a2, __int_as_float(p2.y), d2);
      fma4(a3, __int_as_float(p3.y), d3);
      fma4(a0, __int_as_float(p4.y), d4);
      fma4(a1, __int_as_float(p5.y), d5);
      fma4(a2, __int_as_float(p6.y), d6);
      fma4(a3, __int_as_float(p7.y), d7);
    }
    for (; j < e; ++j) {
      int2 ev = pairs[j];
      float4 d = dense4[(size_t)ev.x * 32 + c4];
      fma4(a0, __int_as_float(ev.y), d);
    }
  }
  float4 acc;
  acc.x = (a0.x + a1.x) + (a2.x + a3.x);
  acc.y = (a0.y + a1.y) + (a2.y + a3.y);
  acc.z = (a0.z + a1.z) + (a2.z + a3.z);
  acc.w = (a0.w + a1.w) + (a2.w + a3.w);
  if (EPI) {
    float4 b = ((const float4*)bias)[c4];
    acc.x = fmaxf(acc.x + b.x, 0.f);
    acc.y = fmaxf(acc.y + b.y, 0.f);
    acc.z = fmaxf(acc.z + b.z, 0.f);
    acc.w = fmaxf(acc.w + b.w, 0.f);
  }
  if (WF32)
    *(float4*)(outf + (size_t)r * 128 + c4 * 4) = acc;
  if (WB16) {
    us4 h = {f2bf(acc.x), f2bf(acc.y), f2bf(acc.z), f2bf(acc.w)};
    *(us4*)(outb + (size_t)r * 128 + c4 * 4) = h;
  }
}

// ---------------------------------------------------------------------------
// bf16-MFMA GEMM: C[M,N] = A[M,K]@B[K,N] (+bias,relu if EPI). B fp32.
// A fp32 (converted during staging) or bf16 (ABF16 - staged directly).
// C fp32 or bf16 (OUTB). 128x128 tile, BK=32, 4 waves, 16x16x32 MFMA.
// LDS fragment-major: MFMA-side reads are linear ds_read_b128, conflict-free.
// ---------------------------------------------------------------------------
template <int K, int N, bool EPI, bool ABF16, bool OUTB>
__global__ __launch_bounds__(256) void gemm_mfma_kernel(
    const void* __restrict__ Av, const float* __restrict__ B,
    const float* __restrict__ bias, void* __restrict__ Cv, int M) {
  __shared__ __align__(16) unsigned short Alds[4096];  // 128x32 bf16
  __shared__ __align__(16) unsigned short Blds[4096];  // 32x128 bf16
  int tid = threadIdx.x;
  int lane = tid & 63, wid = tid >> 6;
  int wm = wid >> 1, wn = wid & 1;          // 2x2 wave grid
  int rowBase = blockIdx.x * 128;
  int colBase = blockIdx.y * 128;
  // A staging coords: thread covers (m = p*32 + tid>>3, k = (tid&7)*4)
  int kg = tid & 7, mrow = tid >> 3;
  int aquad = kg >> 1, aj0 = (kg & 1) * 4;
  // B staging coords: thread covers (col = tid&127, k = p*8 + (tid>>7)*4)
  int bn = tid & 127, kh = tid >> 7;
  int NTb = bn >> 4, nloc = bn & 15;

  f32x4 acc[4][4];
#pragma unroll
  for (int mt = 0; mt < 4; ++mt)
#pragma unroll
    for (int nt = 0; nt < 4; ++nt)
      acc[mt][nt] = (f32x4){0.f, 0.f, 0.f, 0.f};

  for (int kb = 0; kb < K; kb += 32) {
    // ---- global loads ----
    float4 av[4];
    us4 av16[4];
    if constexpr (ABF16) {
      const unsigned short* A = (const unsigned short*)Av;
#pragma unroll
      for (int p = 0; p < 4; ++p) {
        int r = rowBase + p * 32 + mrow;
        av16[p] = (r < M) ? *(const us4*)(A + (size_t)r * K + kb + kg * 4)
                          : (us4){0, 0, 0, 0};
      }
    } else {
      const float* A = (const float*)Av;
#pragma unroll
      for (int p = 0; p < 4; ++p) {
        int r = rowBase + p * 32 + mrow;
        av[p] = (r < M) ? *(const float4*)(A + (size_t)r * K + kb + kg * 4)
                        : make_float4(0.f, 0.f, 0.f, 0.f);
      }
    }
    float bv[4][4];
#pragma unroll
    for (int p = 0; p < 4; ++p) {
      int k = p * 8 + kh * 4;
#pragma unroll
      for (int i = 0; i < 4; ++i)
        bv[p][i] = B[(size_t)(kb + k + i) * N + colBase + bn];
    }
    __syncthreads();  // previous iteration's LDS reads complete
    // ---- convert + LDS store (fragment-major) ----
#pragma unroll
    for (int p = 0; p < 4; ++p) {
      int m = p * 32 + mrow;
      int MT = m >> 4, mloc = m & 15;
      us4 h;
      if constexpr (ABF16) h = av16[p];
      else h = (us4){f2bf(av[p].x), f2bf(av[p].y), f2bf(av[p].z), f2bf(av[p].w)};
      *(us4*)&Alds[(((MT * 4 + aquad) * 16 + mloc) << 3) + aj0] = h;
    }
#pragma unroll
    for (int p = 0; p < 4; ++p) {
      us4 h = {f2bf(bv[p][0]), f2bf(bv[p][1]), f2bf(bv[p][2]), f2bf(bv[p][3])};
      *(us4*)&Blds[(((NTb * 4 + p) * 16 + nloc) << 3) + kh * 4] = h;
    }
    __syncthreads();
    // ---- MFMA ----
    bf16x8 af[4], bf[4];
#pragma unroll
    for (int mt = 0; mt < 4; ++mt)
      af[mt] = *(bf16x8*)&Alds[(((wm * 4 + mt) * 64 + lane)) << 3];
#pragma unroll
    for (int nt = 0; nt < 4; ++nt)
      bf[nt] = *(bf16x8*)&Blds[(((wn * 4 + nt) * 64 + lane)) << 3];
#pragma unroll
    for (int mt = 0; mt < 4; ++mt)
#pragma unroll
      for (int nt = 0; nt < 4; ++nt)
        acc[mt][nt] = __builtin_amdgcn_mfma_f32_16x16x32_bf16(
            af[mt], bf[nt], acc[mt][nt], 0, 0, 0);
  }
  // ---- epilogue: C/D layout col=lane&15, row=(lane>>4)*4+i ----
  int cquad = lane >> 4, cn = lane & 15;
#pragma unroll
  for (int nt = 0; nt < 4; ++nt) {
    int col = colBase + wn * 64 + nt * 16 + cn;
    float bb = EPI ? bias[col] : 0.f;
#pragma unroll
    for (int mt = 0; mt < 4; ++mt) {
      int r0 = rowBase + wm * 64 + mt * 16 + cquad * 4;
#pragma unroll
      for (int i = 0; i < 4; ++i) {
        int r = r0 + i;
        if (r < M) {
          float o = acc[mt][nt][i];
          if (EPI) o = fmaxf(o + bb, 0.f);
          if constexpr (OUTB)
            ((unsigned short*)Cv)[(size_t)r * N + col] = f2bf(o);
          else
            ((float*)Cv)[(size_t)r * N + col] = o;
        }
      }
    }
  }
}

// ---------------------------------------------------------------------------
extern "C" void kernel_launch(void* const* d_in, const int* in_sizes, int n_in,
                              void* d_out, int out_size, void* d_ws, size_t ws_size,
                              hipStream_t stream) {
  const float* x        = (const float*)d_in[0];
  const int*   adj_row  = (const int*)d_in[1];
  const int*   adj_col  = (const int*)d_in[2];
  const float* adj_val  = (const float*)d_in[3];
  const int*   ainv_row = (const int*)d_in[4];
  const int*   ainv_col = (const int*)d_in[5];
  const float* ainv_val = (const float*)d_in[6];
  const float* W1       = (const float*)d_in[7];
  const float* b1       = (const float*)d_in[8];
  const float* W2       = (const float*)d_in[9];
  const float* b2       = (const float*)d_in[10];

  float* out = (float*)d_out;                    // [N,512]
  float* emb = out + (size_t)NN * NFEAT;         // [N,128] (fp32 output)

  // Workspace carve (256B-aligned chunks)
  size_t off = 0;
  auto carve = [&](size_t bytes) {
    void* p = (char*)d_ws + off;
    off += (bytes + 255) & ~(size_t)255;
    return p;
  };
  unsigned short* Tb   = (unsigned short*)carve((size_t)NN * HIDD * 2);  // 12.8MB
  unsigned short* H0b  = (unsigned short*)carve((size_t)NN * HIDD * 2);  // 12.8MB
  int*  rowptr_a = (int*)carve(50004 * 4);
  int*  rowptr_b = (int*)carve(50004 * 4);
  unsigned int* cnt_a = (unsigned int*)carve((size_t)NCH * NWRD * 4);    // 6.4MB
  unsigned int* cnt_b = (unsigned int*)carve((size_t)NCH * NWRD * 4);    // 6.4MB
  int*  base_a   = (int*)carve((size_t)NCH * NN * 4);                     // 12.8MB
  int*  base_b   = (int*)carve((size_t)NCH * NN * 4);                     // 12.8MB
  int*  bsum_a   = (int*)carve(256 * 4);
  int*  bsum_b   = (int*)carve(256 * 4);
  int2* pairs_a  = (int2*)carve((size_t)NE * 8);                          // 12.8MB
  int2* pairs_b  = (int2*)carve((size_t)NE * 8);                          // 12.8MB
  // Optional bf16 copy of emb for spmm2's gather (+12.8MB) — only if ws fits.
  unsigned short* embb = (unsigned short*)((char*)d_ws + off);
  bool full = ws_size >= off + (size_t)NN * HIDD * 2;

  // ---- CSR build for both graphs (LDS-histogram counting sort; 0 global
  //      atomics, no memsets needed — all buffers fully overwritten) ----
  chunk_hist_kernel<<<dim3(NCH, 2), 256, 0, stream>>>(
      adj_row, ainv_row, cnt_a, cnt_b);
  block_sum_kernel<<<dim3(NB, 2), 256, 0, stream>>>(cnt_a, cnt_b, bsum_a, bsum_b, NN);
  scan_partials_kernel<<<2, 256, 0, stream>>>(bsum_a, bsum_b, rowptr_a, rowptr_b,
                                              NB, NN);
  scan_apply_kernel<<<dim3(NB, 2), 256, 0, stream>>>(
      cnt_a, cnt_b, bsum_a, bsum_b, rowptr_a, rowptr_b, base_a, base_b, NN);
  scatter_chunk_kernel<<<dim3(NCH, 2), 256, 0, stream>>>(
      adj_row, adj_col, adj_val, base_a, pairs_a,
      ainv_row, ainv_col, ainv_val, base_b, pairs_b);

  // ---- H0b = bf16(X @ W1) (bf16 MFMA, bf16 out) ----
  gemm_mfma_kernel<NFEAT, HIDD, false, false, true>
      <<<dim3((NN + 127) / 128, 1), 256, 0, stream>>>(x, W1, nullptr, H0b, NN);

  // ---- emb = relu(A @ H0 + b1); also bf16 copy for next gather ----
  if (full)
    spmm_kernel<true, true, true, true><<<(NN + 7) / 8, 256, 0, stream>>>(
        rowptr_a, pairs_a, H0b, b1, emb, embb, NN);
  else
    spmm_kernel<true, true, true, false><<<(NN + 7) / 8, 256, 0, stream>>>(
        rowptr_a, pairs_a, H0b, b1, emb, nullptr, NN);

  // ---- Tb = bf16(A_inv @ emb)  (reassociated: (A_inv @ h) @ W2) ----
  if (full)
    spmm_kernel<true, false, false, true><<<(NN + 7) / 8, 256, 0, stream>>>(
        rowptr_b, pairs_b, embb, nullptr, nullptr, Tb, NN);
  else
    spmm_kernel<false, false, false, true><<<(NN + 7) / 8, 256, 0, stream>>>(
        rowptr_b, pairs_b, emb, nullptr, nullptr, Tb, NN);

  // ---- out = relu(Tb @ W2 + b2) (bf16 MFMA, bf16 A operand) ----
  gemm_mfma_kernel<HIDD, NFEAT, true, true, false>
      <<<dim3((NN + 127) / 128, 4), 256, 0, stream>>>(Tb, W2, b2, out, NN);
}